// Round 1
// 677.387 us; speedup vs baseline: 1.1150x; 1.1150x over previous
//
#include <hip/hip_runtime.h>

// Problem constants (match reference)
#define Bsz 8
#define Ssz 2048
#define PLM 768
#define Gd  256
#define N_WM 50000
#define E_WM 800000
#define N_F  16384   // B*S
#define E_F  131072
#define Kc   4

typedef unsigned short ushort_t;
typedef short short8 __attribute__((ext_vector_type(8)));
typedef float f32x4 __attribute__((ext_vector_type(4)));

// RNE float -> bf16 bits
__device__ __forceinline__ ushort_t f2bf(float f) {
    union { float f; unsigned int u; } v; v.f = f;
    unsigned int r = (v.u + 0x7fffu + ((v.u >> 16) & 1u)) >> 16;
    return (ushort_t)r;
}
__device__ __forceinline__ float bf2f(ushort_t b) {
    union { unsigned int u; float f; } v; v.u = ((unsigned int)b) << 16;
    return v.f;
}
__device__ __forceinline__ float4 bf4f(ushort4 u) {
    return make_float4(bf2f(u.x), bf2f(u.y), bf2f(u.z), bf2f(u.w));
}

// async global->LDS, 16B per lane; LDS dest must be wave-uniform base
__device__ __forceinline__ void gl2lds16(const ushort_t* g, ushort_t* l) {
    __builtin_amdgcn_global_load_lds(
        (const __attribute__((address_space(1))) unsigned int*)g,
        (__attribute__((address_space(3))) unsigned int*)l, 16, 0, 0);
}

// ---------------------------------------------------------------------------
// fp32 -> bf16 bulk convert (n4 = n/4 float4s)
// ---------------------------------------------------------------------------
__global__ void cvt_bf_kernel(const float* __restrict__ in,
                              ushort_t* __restrict__ out, int n4) {
    int i = blockIdx.x * 256 + threadIdx.x;
    if (i < n4) {
        float4 v = ((const float4*)in)[i];
        ushort4 u;
        u.x = f2bf(v.x); u.y = f2bf(v.y); u.z = f2bf(v.z); u.w = f2bf(v.w);
        ((ushort4*)out)[i] = u;
    }
}

// W[k][n] fp32 -> Wt[n][k] bf16
__global__ void wt_kernel(const float* __restrict__ W, ushort_t* __restrict__ Wt,
                          int K, int N) {
    int idx = blockIdx.x * 256 + threadIdx.x;
    if (idx < N * K) {
        int n = idx / K, k = idx % K;
        Wt[idx] = f2bf(W[(size_t)k * N + n]);
    }
}

// ---------------------------------------------------------------------------
// CSR build: histogram -> 3-phase parallel exclusive scan -> bucket fill
// ---------------------------------------------------------------------------
__global__ void hist_kernel(const int* __restrict__ dst, int* __restrict__ cnt, int E) {
    int e = blockIdx.x * 256 + threadIdx.x;
    if (e < E) atomicAdd(&cnt[dst[e]], 1);
}

// phase 1: per-block (1024 elems) sum -> bsum[b]
__global__ __launch_bounds__(256) void scan_part1(const int* __restrict__ cnt,
                                                  int* __restrict__ bsum, int n) {
    __shared__ int sm[256];
    int t = threadIdx.x;
    int base = blockIdx.x * 1024 + t * 4;
    int s = 0;
    if (base + 3 < n) {
        int4 q = *(const int4*)&cnt[base];
        s = q.x + q.y + q.z + q.w;
    } else {
#pragma unroll
        for (int i = 0; i < 4; ++i) if (base + i < n) s += cnt[base + i];
    }
    sm[t] = s; __syncthreads();
#pragma unroll
    for (int st = 128; st > 0; st >>= 1) {
        if (t < st) sm[t] += sm[t + st];
        __syncthreads();
    }
    if (t == 0) bsum[blockIdx.x] = sm[0];
}

// phase 2: exclusive scan of block sums (nb <= 64, trivial)
__global__ void scan_bsums(int* __restrict__ bsum, int nb) {
    if (threadIdx.x == 0 && blockIdx.x == 0) {
        int acc = 0;
        for (int i = 0; i < nb; ++i) { int c = bsum[i]; bsum[i] = acc; acc += c; }
    }
}

// phase 3: in-block scan + add block base; write off[] and cursor (cnt[])
__global__ __launch_bounds__(256) void scan_part2(int* __restrict__ cnt,
                                                  int* __restrict__ off,
                                                  const int* __restrict__ bsum,
                                                  int n, int total) {
    __shared__ int sm[256];
    int t = threadIdx.x;
    int base = blockIdx.x * 1024 + t * 4;
    int v0 = 0, v1 = 0, v2 = 0, v3 = 0;
    if (base + 3 < n) {
        int4 q = *(const int4*)&cnt[base];
        v0 = q.x; v1 = q.y; v2 = q.z; v3 = q.w;
    } else {
        if (base + 0 < n) v0 = cnt[base + 0];
        if (base + 1 < n) v1 = cnt[base + 1];
        if (base + 2 < n) v2 = cnt[base + 2];
        if (base + 3 < n) v3 = cnt[base + 3];
    }
    int s = v0 + v1 + v2 + v3;
    sm[t] = s;
    __syncthreads();
#pragma unroll
    for (int st = 1; st < 256; st <<= 1) {
        int x = (t >= st) ? sm[t - st] : 0;
        __syncthreads();
        sm[t] += x;
        __syncthreads();
    }
    int ex = bsum[blockIdx.x] + sm[t] - s;   // exclusive prefix of this thread
    int o0 = ex, o1 = ex + v0, o2 = o1 + v1, o3 = o2 + v2;
    if (base + 0 < n) { off[base + 0] = o0; cnt[base + 0] = o0; }
    if (base + 1 < n) { off[base + 1] = o1; cnt[base + 1] = o1; }
    if (base + 2 < n) { off[base + 2] = o2; cnt[base + 2] = o2; }
    if (base + 3 < n) { off[base + 3] = o3; cnt[base + 3] = o3; }
    if (blockIdx.x == 0 && t == 0) off[n] = total;
}

__global__ void fill_kernel(const int* __restrict__ src, const int* __restrict__ dst,
                            int* __restrict__ cur, int* __restrict__ bucket, int E) {
    int e = blockIdx.x * 256 + threadIdx.x;
    if (e < E) {
        int p = atomicAdd(&cur[dst[e]], 1);
        bucket[p] = src[e];
    }
}

// ---------------------------------------------------------------------------
// aggregate (bf16): hm[i] = h[i] + sum_{j in CSR(i)} h[bucket[j]]
// one wave per node, ushort4 (8B) per lane, fp32 accumulate.
// Latency-bound fix: 8-deep manual batch -> 8 independent row gathers in
// flight per wave (was 1: serial bucket->row dependent chain, 90.8 us).
// ---------------------------------------------------------------------------
__global__ void aggregate_kernel(const ushort_t* __restrict__ h,
                                 const int* __restrict__ off,
                                 const int* __restrict__ bucket,
                                 ushort_t* __restrict__ hm, int n) {
    int i = blockIdx.x * 4 + (threadIdx.x >> 6);
    if (i >= n) return;
    int lane = threadIdx.x & 63;
    int s0 = off[i], s1 = off[i + 1];
    const ushort4* hp = (const ushort4*)h;   // 64 ushort4 per row
    float4 acc = bf4f(hp[(size_t)i * 64 + lane]);
    int j = s0;
    // ---- 8-wide batches: load 8 indices, then 8 independent row loads ----
    for (; j + 8 <= s1; j += 8) {
        int b0 = bucket[j + 0], b1 = bucket[j + 1];
        int b2 = bucket[j + 2], b3 = bucket[j + 3];
        int b4 = bucket[j + 4], b5 = bucket[j + 5];
        int b6 = bucket[j + 6], b7 = bucket[j + 7];
        ushort4 r0 = hp[(size_t)b0 * 64 + lane];
        ushort4 r1 = hp[(size_t)b1 * 64 + lane];
        ushort4 r2 = hp[(size_t)b2 * 64 + lane];
        ushort4 r3 = hp[(size_t)b3 * 64 + lane];
        ushort4 r4 = hp[(size_t)b4 * 64 + lane];
        ushort4 r5 = hp[(size_t)b5 * 64 + lane];
        ushort4 r6 = hp[(size_t)b6 * 64 + lane];
        ushort4 r7 = hp[(size_t)b7 * 64 + lane];
        float4 v0 = bf4f(r0), v1 = bf4f(r1), v2 = bf4f(r2), v3 = bf4f(r3);
        float4 v4 = bf4f(r4), v5 = bf4f(r5), v6 = bf4f(r6), v7 = bf4f(r7);
        acc.x += v0.x + v1.x + v2.x + v3.x + v4.x + v5.x + v6.x + v7.x;
        acc.y += v0.y + v1.y + v2.y + v3.y + v4.y + v5.y + v6.y + v7.y;
        acc.z += v0.z + v1.z + v2.z + v3.z + v4.z + v5.z + v6.z + v7.z;
        acc.w += v0.w + v1.w + v2.w + v3.w + v4.w + v5.w + v6.w + v7.w;
    }
    // ---- 2-wide tail ----
    for (; j + 2 <= s1; j += 2) {
        int b0 = bucket[j + 0], b1 = bucket[j + 1];
        ushort4 r0 = hp[(size_t)b0 * 64 + lane];
        ushort4 r1 = hp[(size_t)b1 * 64 + lane];
        float4 v0 = bf4f(r0), v1 = bf4f(r1);
        acc.x += v0.x + v1.x; acc.y += v0.y + v1.y;
        acc.z += v0.z + v1.z; acc.w += v0.w + v1.w;
    }
    // ---- 1-wide tail ----
    if (j < s1) {
        int b0 = bucket[j];
        float4 v0 = bf4f(hp[(size_t)b0 * 64 + lane]);
        acc.x += v0.x; acc.y += v0.y; acc.z += v0.z; acc.w += v0.w;
    }
    ushort4 u;
    u.x = f2bf(acc.x); u.y = f2bf(acc.y); u.z = f2bf(acc.z); u.w = f2bf(acc.w);
    ((ushort4*)hm)[(size_t)i * 64 + lane] = u;
}

// ---------------------------------------------------------------------------
// tmp[i] = sum_k table[token2nodepos[i,k]+2]   (bf16 table, fp32 accumulate)
// ---------------------------------------------------------------------------
__global__ void tmp_kernel(const ushort_t* __restrict__ gemb,
                           const ushort_t* __restrict__ extra,
                           const int* __restrict__ t2np,
                           ushort_t* __restrict__ D) {
    int i = blockIdx.x * 4 + (threadIdx.x >> 6);
    int lane = threadIdx.x & 63;
    float4 s = make_float4(0.f, 0.f, 0.f, 0.f);
#pragma unroll
    for (int k = 0; k < Kc; ++k) {
        int idx = t2np[i * Kc + k] + 2;
        const ushort4* row = (idx < 2) ? (const ushort4*)(extra + (size_t)idx * Gd)
                                       : (const ushort4*)(gemb + (size_t)(idx - 2) * Gd);
        float4 v = bf4f(row[lane]);
        s.x += v.x; s.y += v.y; s.z += v.z; s.w += v.w;
    }
    ushort4 u;
    u.x = f2bf(s.x); u.y = f2bf(s.y); u.z = f2bf(s.z); u.w = f2bf(s.w);
    ((ushort4*)D)[(size_t)i * 64 + lane] = u;
}

// ---------------------------------------------------------------------------
// row gather (bf16): F[i] = E[ids[i]]
// ---------------------------------------------------------------------------
__global__ void gather_kernel(const ushort_t* __restrict__ Ein,
                              const int* __restrict__ ids,
                              ushort_t* __restrict__ F) {
    int i = blockIdx.x * 4 + (threadIdx.x >> 6);
    int lane = threadIdx.x & 63;
    ((ushort4*)F)[(size_t)i * 64 + lane] =
        ((const ushort4*)Ein)[(size_t)ids[i] * 64 + lane];
}

// ---------------------------------------------------------------------------
// bf16 MFMA GEMM, m97 structure: 128x128 tile, BK=64, global_load_lds width 16
// A operand bf16 (row-major in k), B = pre-transposed bf16 Wt[n][k].
// MODE 0: A = p0[row][k], rowlen K
// MODE 2: A = k<256 ? p0[row][k] : p1(row, k-256) rowlen 768     (tmp|text), K=1024
// MODE 3: A = k<768 ? p0 : k<1024 ? p1 : p2                      (text|tmp|temporal), K=1280
// OUTBF: 1 -> bf16 C, 0 -> fp32 C
// ---------------------------------------------------------------------------
#define TBM 128
#define TBN 128
#define TBK 64

template <int MODE, int OUTBF>
__global__ __launch_bounds__(256) void mfma_gemm(
    const ushort_t* __restrict__ p0, const ushort_t* __restrict__ p1,
    const ushort_t* __restrict__ p2, const ushort_t* __restrict__ Wt,
    const float* __restrict__ bias, void* __restrict__ Cv,
    int M, int N, int K, int relu) {
    __shared__ ushort_t As[TBM * TBK];   // [row][k], stride 64, no pad (lds-dma)
    __shared__ ushort_t Bs[TBN * TBK];   // [col][k]

    int tid  = threadIdx.x;
    int lane = tid & 63;
    int wave = tid >> 6;
    int wm = (wave >> 1) * 64, wn = (wave & 1) * 64;
    int row0 = blockIdx.y * TBM, col0 = blockIdx.x * TBN;
    int l15 = lane & 15, l4 = lane >> 4;

    f32x4 acc[4][4];
#pragma unroll
    for (int i = 0; i < 4; ++i)
#pragma unroll
        for (int j = 0; j < 4; ++j)
            acc[i][j] = (f32x4){0.f, 0.f, 0.f, 0.f};

    for (int k0 = 0; k0 < K; k0 += TBK) {
        // ---- stage A via lds-dma: 16KB, 4 iters x (4 waves x 1KB) ----
#pragma unroll
        for (int it = 0; it < 4; ++it) {
            int eb = it * 2048 + wave * 512;   // wave-uniform elem base
            int le = eb + lane * 8;
            int r  = le >> 6;
            int kl = le & 63;
            int grow = row0 + r; if (grow > M - 1) grow = M - 1;
            int gk = k0 + kl;
            const ushort_t* gp;
            if (MODE == 0)
                gp = p0 + (size_t)grow * K + gk;
            else if (MODE == 2)
                gp = (gk < 256) ? p0 + (size_t)grow * 256 + gk
                                : p1 + (size_t)grow * 768 + (gk - 256);
            else
                gp = (gk < 768) ? p0 + (size_t)grow * 768 + gk
                   : (gk < 1024) ? p1 + (size_t)grow * 256 + (gk - 768)
                                 : p2 + (size_t)grow * 256 + (gk - 1024);
            gl2lds16(gp, &As[eb]);
        }
        // ---- stage B via lds-dma ----
#pragma unroll
        for (int it = 0; it < 4; ++it) {
            int eb = it * 2048 + wave * 512;
            int le = eb + lane * 8;
            int nl = le >> 6;
            int kl = le & 63;
            const ushort_t* gp = Wt + (size_t)(col0 + nl) * K + k0 + kl;
            gl2lds16(gp, &Bs[eb]);
        }
        __syncthreads();

#pragma unroll
        for (int ks = 0; ks < TBK; ks += 32) {
            short8 af[4], bfr[4];
#pragma unroll
            for (int mi = 0; mi < 4; ++mi)
                af[mi] = *(const short8*)&As[(wm + mi * 16 + l15) * TBK + ks + l4 * 8];
#pragma unroll
            for (int ni = 0; ni < 4; ++ni)
                bfr[ni] = *(const short8*)&Bs[(wn + ni * 16 + l15) * TBK + ks + l4 * 8];
#pragma unroll
            for (int mi = 0; mi < 4; ++mi)
#pragma unroll
                for (int ni = 0; ni < 4; ++ni)
                    acc[mi][ni] = __builtin_amdgcn_mfma_f32_16x16x32_bf16(
                        af[mi], bfr[ni], acc[mi][ni], 0, 0, 0);
        }
        __syncthreads();
    }

    // ---- epilogue: bias (+relu); C/D layout col=lane&15, row=(lane>>4)*4+reg ----
#pragma unroll
    for (int ni = 0; ni < 4; ++ni) {
        int c = col0 + wn + ni * 16 + l15;
        float bv = bias[c];
#pragma unroll
        for (int mi = 0; mi < 4; ++mi) {
#pragma unroll
            for (int r = 0; r < 4; ++r) {
                int rr = row0 + wm + mi * 16 + l4 * 4 + r;
                if (rr < M) {
                    float v = acc[mi][ni][r] + bv;
                    if (relu) v = fmaxf(v, 0.f);
                    if (OUTBF) ((ushort_t*)Cv)[(size_t)rr * N + c] = f2bf(v);
                    else       ((float*)Cv)[(size_t)rr * N + c] = v;
                }
            }
        }
    }
}

// ---------------------------------------------------------------------------
extern "C" void kernel_launch(void* const* d_in, const int* in_sizes, int n_in,
                              void* d_out, int out_size, void* d_ws, size_t ws_size,
                              hipStream_t stream) {
    const float* text    = (const float*)d_in[0];   // [16384, 768]
    const float* wm_x    = (const float*)d_in[1];   // [50000, 256]
    const int*   wm_ei   = (const int*)d_in[2];     // [2, 800000]
    const int*   t2np    = (const int*)d_in[3];     // [16384, 4]
    const int*   f_ids   = (const int*)d_in[4];     // [16384]
    const int*   f_ei    = (const int*)d_in[5];     // [2, 131072]
    const float* extra   = (const float*)d_in[6];   // [2, 256]
    const float* wm_W1   = (const float*)d_in[7];
    const float* wm_b1   = (const float*)d_in[8];
    const float* wm_W2   = (const float*)d_in[9];
    const float* wm_b2   = (const float*)d_in[10];
    const float* fs_W1   = (const float*)d_in[11];
    const float* fs_b1   = (const float*)d_in[12];
    const float* fs_W2   = (const float*)d_in[13];
    const float* fs_b2   = (const float*)d_in[14];
    const float* fc1_W   = (const float*)d_in[15];  // [1024, 256]
    const float* fc1_b   = (const float*)d_in[16];
    const float* fc3_W   = (const float*)d_in[17];  // [1280, 768]
    const float* fc3_b   = (const float*)d_in[18];
    float* out = (float*)d_out;                     // [16384, 768]

    // ---- workspace layout (bf16 = ushort) ----
    ushort_t* Xb  = (ushort_t*)d_ws;            // [50000*256] wm_x bf16 (reused: h1)
    ushort_t* Ag  = Xb + 12800000;              // [50000*256] aggregate out
    ushort_t* Gm  = Ag + 12800000;              // [50000*256] gemb (reused: F, H)
    ushort_t* Tx  = Gm + 12800000;              // [16384*768] text bf16
    ushort_t* Dt  = Tx + 12582912;              // [16384*256] tmp
    ushort_t* Ee  = Dt + 4194304;               // [16384*256] gte (reused: T)
    ushort_t* Wv  = Ee + 4194304;               // weights, transposed bf16
    ushort_t* wt_wm1 = Wv;                      //  65536
    ushort_t* wt_wm2 = wt_wm1 + 65536;          //  65536
    ushort_t* wt_fs1 = wt_wm2 + 65536;          //  65536
    ushort_t* wt_fs2 = wt_fs1 + 65536;          //  65536
    ushort_t* wt_fc1 = wt_fs2 + 65536;          //  262144
    ushort_t* wt_fc3 = wt_fc1 + 262144;         //  983040
    ushort_t* Exb    = wt_fc3 + 983040;         //  512
    int* wm_off = (int*)(Exb + 512);            // [N_WM+1]
    int* wm_cnt = wm_off + N_WM + 1;
    int* wm_bkt = wm_cnt + N_WM;                // [E_WM]
    int* fs_off = wm_bkt + E_WM;                // [N_F+1]
    int* fs_cnt = fs_off + N_F + 1;
    int* fs_bkt = fs_cnt + N_F;                 // [E_F]
    int* bsum_wm = fs_bkt + E_F;                // [64]
    int* bsum_fs = bsum_wm + 64;                // [16]

    ushort_t* h1 = Xb;                 // gemm1 out overwrites Xb (dead)
    ushort_t* F  = Gm;                 // gather out overwrites gemb (dead)
    ushort_t* H  = Gm + 4194304;
    ushort_t* T  = Ee;                 // fstm out overwrites Ee (dead)

    const int* wm_src = wm_ei;
    const int* wm_dst = wm_ei + E_WM;
    const int* f_src  = f_ei;
    const int* f_dst  = f_ei + E_F;

    dim3 blk(256);
    dim3 gW(Gd / TBN, (N_WM + TBM - 1) / TBM);   // 2 x 391
    dim3 gF(Gd / TBN, N_F / TBM);                // 2 x 128
    dim3 gO(PLM / TBN, N_F / TBM);               // 6 x 128

    const int nbW = (N_WM + 1023) / 1024;   // 49
    const int nbF = (N_F + 1023) / 1024;    // 16

    // ===== CSR build =====
    hipMemsetAsync(wm_cnt, 0, N_WM * sizeof(int), stream);
    hipMemsetAsync(fs_cnt, 0, N_F * sizeof(int), stream);
    hist_kernel<<<(E_WM + 255) / 256, blk, 0, stream>>>(wm_dst, wm_cnt, E_WM);
    hist_kernel<<<(E_F + 255) / 256, blk, 0, stream>>>(f_dst, fs_cnt, E_F);
    scan_part1<<<nbW, blk, 0, stream>>>(wm_cnt, bsum_wm, N_WM);
    scan_part1<<<nbF, blk, 0, stream>>>(fs_cnt, bsum_fs, N_F);
    scan_bsums<<<1, 64, 0, stream>>>(bsum_wm, nbW);
    scan_bsums<<<1, 64, 0, stream>>>(bsum_fs, nbF);
    scan_part2<<<nbW, blk, 0, stream>>>(wm_cnt, wm_off, bsum_wm, N_WM, E_WM);
    scan_part2<<<nbF, blk, 0, stream>>>(fs_cnt, fs_off, bsum_fs, N_F, E_F);
    fill_kernel<<<(E_WM + 255) / 256, blk, 0, stream>>>(wm_src, wm_dst, wm_cnt, wm_bkt, E_WM);
    fill_kernel<<<(E_F + 255) / 256, blk, 0, stream>>>(f_src, f_dst, fs_cnt, fs_bkt, E_F);

    // ===== one-time conversions =====
    cvt_bf_kernel<<<(3200000 + 255) / 256, blk, 0, stream>>>(wm_x, Xb, 3200000);
    cvt_bf_kernel<<<(3145728 + 255) / 256, blk, 0, stream>>>(text, Tx, 3145728);
    cvt_bf_kernel<<<1, blk, 0, stream>>>(extra, Exb, 128);
    wt_kernel<<<(65536 + 255) / 256, blk, 0, stream>>>(wm_W1, wt_wm1, 256, 256);
    wt_kernel<<<(65536 + 255) / 256, blk, 0, stream>>>(wm_W2, wt_wm2, 256, 256);
    wt_kernel<<<(65536 + 255) / 256, blk, 0, stream>>>(fs_W1, wt_fs1, 256, 256);
    wt_kernel<<<(65536 + 255) / 256, blk, 0, stream>>>(fs_W2, wt_fs2, 256, 256);
    wt_kernel<<<(262144 + 255) / 256, blk, 0, stream>>>(fc1_W, wt_fc1, 1024, 256);
    wt_kernel<<<(983040 + 255) / 256, blk, 0, stream>>>(fc3_W, wt_fc3, 1280, 768);

    // ===== WM layer 1 =====
    aggregate_kernel<<<(N_WM + 3) / 4, blk, 0, stream>>>(Xb, wm_off, wm_bkt, Ag, N_WM);
    mfma_gemm<0, 1><<<gW, blk, 0, stream>>>(Ag, nullptr, nullptr, wt_wm1, wm_b1,
                                            h1, N_WM, Gd, Gd, 1);
    // ===== WM layer 2 =====
    aggregate_kernel<<<(N_WM + 3) / 4, blk, 0, stream>>>(h1, wm_off, wm_bkt, Ag, N_WM);
    mfma_gemm<0, 1><<<gW, blk, 0, stream>>>(Ag, nullptr, nullptr, wt_wm2, wm_b2,
                                            Gm, N_WM, Gd, Gd, 1);
    // ===== tmp =====
    tmp_kernel<<<N_F / 4, blk, 0, stream>>>(Gm, Exb, t2np, Dt);
    // ===== fc1: Ee = concat(tmp, text) @ fc1_W + b =====
    mfma_gemm<2, 1><<<gF, blk, 0, stream>>>(Dt, Tx, nullptr, wt_fc1, fc1_b,
                                            Ee, N_F, Gd, Gd + PLM, 0);
    // ===== FSTM gather =====
    gather_kernel<<<N_F / 4, blk, 0, stream>>>(Ee, f_ids, F);
    // ===== FSTM layer 1 =====
    aggregate_kernel<<<N_F / 4, blk, 0, stream>>>(F, fs_off, fs_bkt, Ag, N_F);
    mfma_gemm<0, 1><<<gF, blk, 0, stream>>>(Ag, nullptr, nullptr, wt_fs1, fs_b1,
                                            H, N_F, Gd, Gd, 1);
    // ===== FSTM layer 2 =====
    aggregate_kernel<<<N_F / 4, blk, 0, stream>>>(H, fs_off, fs_bkt, Ag, N_F);
    mfma_gemm<0, 1><<<gF, blk, 0, stream>>>(Ag, nullptr, nullptr, wt_fs2, fs_b2,
                                            T, N_F, Gd, Gd, 1);
    // ===== fc3: out = concat(text, tmp, temporal) @ fc3_W + b (fp32 out) =====
    mfma_gemm<3, 0><<<gO, blk, 0, stream>>>(Tx, Dt, T, wt_fc3, fc3_b,
                                            out, N_F, PLM, PLM + 2 * Gd, 0);
}

// Round 2
// 634.327 us; speedup vs baseline: 1.1907x; 1.0679x over previous
//
#include <hip/hip_runtime.h>

// Problem constants (match reference)
#define Bsz 8
#define Ssz 2048
#define PLM 768
#define Gd  256
#define N_WM 50000
#define E_WM 800000
#define N_F  16384   // B*S
#define E_F  131072
#define Kc   4

typedef unsigned short ushort_t;
typedef short short8 __attribute__((ext_vector_type(8)));
typedef float f32x4 __attribute__((ext_vector_type(4)));

// RNE float -> bf16 bits
__device__ __forceinline__ ushort_t f2bf(float f) {
    union { float f; unsigned int u; } v; v.f = f;
    unsigned int r = (v.u + 0x7fffu + ((v.u >> 16) & 1u)) >> 16;
    return (ushort_t)r;
}
__device__ __forceinline__ float bf2f(ushort_t b) {
    union { unsigned int u; float f; } v; v.u = ((unsigned int)b) << 16;
    return v.f;
}
__device__ __forceinline__ float4 bf4f(ushort4 u) {
    return make_float4(bf2f(u.x), bf2f(u.y), bf2f(u.z), bf2f(u.w));
}

// async global->LDS, 16B per lane; LDS dest must be wave-uniform base
__device__ __forceinline__ void gl2lds16(const ushort_t* g, ushort_t* l) {
    __builtin_amdgcn_global_load_lds(
        (const __attribute__((address_space(1))) unsigned int*)g,
        (__attribute__((address_space(3))) unsigned int*)l, 16, 0, 0);
}

// ---------------------------------------------------------------------------
// fused one-time conversions: cvt wm_x, cvt text, cvt extra, 6 weight
// transposes — one dispatch instead of 9.
// ---------------------------------------------------------------------------
__device__ __forceinline__ void cvt4(const float* __restrict__ in,
                                     ushort_t* __restrict__ out, int i, int n4) {
    if (i < n4) {
        float4 v = ((const float4*)in)[i];
        ushort4 u;
        u.x = f2bf(v.x); u.y = f2bf(v.y); u.z = f2bf(v.z); u.w = f2bf(v.w);
        ((ushort4*)out)[i] = u;
    }
}
__device__ __forceinline__ void wtx(const float* __restrict__ W,
                                    ushort_t* __restrict__ Wt, int K, int N, int idx) {
    if (idx < N * K) {
        int n = idx / K, k = idx % K;
        Wt[idx] = f2bf(W[(size_t)k * N + n]);
    }
}

// block ranges: 12500 (wm_x) | 12288 (text) | 1 (extra) | 256x4 (256^2 wt)
//             | 1024 (fc1 wt) | 3840 (fc3 wt)   => total 30677 blocks
__global__ void conv_all(const float* __restrict__ wm_x, const float* __restrict__ text,
                         const float* __restrict__ extra,
                         const float* __restrict__ W1, const float* __restrict__ W2,
                         const float* __restrict__ W3, const float* __restrict__ W4,
                         const float* __restrict__ W5, const float* __restrict__ W6,
                         ushort_t* __restrict__ Xb, ushort_t* __restrict__ Tx,
                         ushort_t* __restrict__ Exb,
                         ushort_t* __restrict__ T1, ushort_t* __restrict__ T2,
                         ushort_t* __restrict__ T3, ushort_t* __restrict__ T4,
                         ushort_t* __restrict__ T5, ushort_t* __restrict__ T6) {
    int b = blockIdx.x, t = threadIdx.x;
    if (b < 12500) { cvt4(wm_x, Xb, b * 256 + t, 3200000); return; }
    b -= 12500;
    if (b < 12288) { cvt4(text, Tx, b * 256 + t, 3145728); return; }
    b -= 12288;
    if (b < 1) { cvt4(extra, Exb, t, 128); return; }
    b -= 1;
    if (b < 256) { wtx(W1, T1, 256, 256, b * 256 + t); return; }
    b -= 256;
    if (b < 256) { wtx(W2, T2, 256, 256, b * 256 + t); return; }
    b -= 256;
    if (b < 256) { wtx(W3, T3, 256, 256, b * 256 + t); return; }
    b -= 256;
    if (b < 256) { wtx(W4, T4, 256, 256, b * 256 + t); return; }
    b -= 256;
    if (b < 1024) { wtx(W5, T5, 1024, 256, b * 256 + t); return; }
    b -= 1024;
    wtx(W6, T6, 1280, 768, b * 256 + t);
}

// ---------------------------------------------------------------------------
// CSR build (both graphs fused): histogram -> scan -> bucket fill
// ---------------------------------------------------------------------------
__global__ void hist_both(const int* __restrict__ wm_dst, int* __restrict__ wm_cnt,
                          const int* __restrict__ f_dst, int* __restrict__ fs_cnt) {
    int e = blockIdx.x * 256 + threadIdx.x;
    if (e < E_WM) {
        atomicAdd(&wm_cnt[wm_dst[e]], 1);
    } else {
        int e2 = e - E_WM;
        if (e2 < E_F) atomicAdd(&fs_cnt[f_dst[e2]], 1);
    }
}

__global__ void fill_both(const int* __restrict__ wm_src, const int* __restrict__ wm_dst,
                          int* __restrict__ wm_cur, int* __restrict__ wm_bkt,
                          const int* __restrict__ f_src, const int* __restrict__ f_dst,
                          int* __restrict__ fs_cur, int* __restrict__ fs_bkt) {
    int e = blockIdx.x * 256 + threadIdx.x;
    if (e < E_WM) {
        int p = atomicAdd(&wm_cur[wm_dst[e]], 1);
        wm_bkt[p] = wm_src[e];
    } else {
        int e2 = e - E_WM;
        if (e2 < E_F) {
            int p = atomicAdd(&fs_cur[f_dst[e2]], 1);
            fs_bkt[p] = f_src[e2];
        }
    }
}

// phase 1: per-block (1024 elems) sum -> bsum[lb]
__device__ __forceinline__ void scan1_body(const int* __restrict__ cnt,
                                           int* __restrict__ bsum, int n, int lb,
                                           int* sm) {
    int t = threadIdx.x;
    int base = lb * 1024 + t * 4;
    int s = 0;
    if (base + 3 < n) {
        int4 q = *(const int4*)&cnt[base];
        s = q.x + q.y + q.z + q.w;
    } else {
#pragma unroll
        for (int i = 0; i < 4; ++i) if (base + i < n) s += cnt[base + i];
    }
    sm[t] = s; __syncthreads();
#pragma unroll
    for (int st = 128; st > 0; st >>= 1) {
        if (t < st) sm[t] += sm[t + st];
        __syncthreads();
    }
    if (t == 0) bsum[lb] = sm[0];
}

#define NBW 49
#define NBF 16
__global__ __launch_bounds__(256) void scan1_both(const int* __restrict__ wm_cnt,
                                                  int* __restrict__ bsum_wm,
                                                  const int* __restrict__ fs_cnt,
                                                  int* __restrict__ bsum_fs) {
    __shared__ int sm[256];
    int b = blockIdx.x;
    if (b < NBW) scan1_body(wm_cnt, bsum_wm, N_WM, b, sm);
    else         scan1_body(fs_cnt, bsum_fs, N_F, b - NBW, sm);
}

// phase 2: exclusive scan of block sums — wave-parallel shfl scan, both graphs
__global__ void scan_bsums_both(int* __restrict__ bw, int* __restrict__ bf) {
    int w = threadIdx.x >> 6, lane = threadIdx.x & 63;
    int* b = w ? bf : bw;
    int nb = w ? NBF : NBW;
    int o = (lane < nb) ? b[lane] : 0;
    int v = o;
#pragma unroll
    for (int off = 1; off < 64; off <<= 1) {
        int t = __shfl_up(v, off, 64);
        if (lane >= off) v += t;
    }
    if (lane < nb) b[lane] = v - o;   // exclusive
}

// phase 3: in-block scan + add block base; write off[] and cursor (cnt[])
__device__ __forceinline__ void scan2_body(int* __restrict__ cnt, int* __restrict__ off,
                                           const int* __restrict__ bsum, int n,
                                           int total, int lb, int* sm) {
    int t = threadIdx.x;
    int base = lb * 1024 + t * 4;
    int v0 = 0, v1 = 0, v2 = 0, v3 = 0;
    if (base + 3 < n) {
        int4 q = *(const int4*)&cnt[base];
        v0 = q.x; v1 = q.y; v2 = q.z; v3 = q.w;
    } else {
        if (base + 0 < n) v0 = cnt[base + 0];
        if (base + 1 < n) v1 = cnt[base + 1];
        if (base + 2 < n) v2 = cnt[base + 2];
        if (base + 3 < n) v3 = cnt[base + 3];
    }
    int s = v0 + v1 + v2 + v3;
    sm[t] = s;
    __syncthreads();
#pragma unroll
    for (int st = 1; st < 256; st <<= 1) {
        int x = (t >= st) ? sm[t - st] : 0;
        __syncthreads();
        sm[t] += x;
        __syncthreads();
    }
    int ex = bsum[lb] + sm[t] - s;   // exclusive prefix of this thread
    int o0 = ex, o1 = ex + v0, o2 = o1 + v1, o3 = o2 + v2;
    if (base + 0 < n) { off[base + 0] = o0; cnt[base + 0] = o0; }
    if (base + 1 < n) { off[base + 1] = o1; cnt[base + 1] = o1; }
    if (base + 2 < n) { off[base + 2] = o2; cnt[base + 2] = o2; }
    if (base + 3 < n) { off[base + 3] = o3; cnt[base + 3] = o3; }
    if (lb == 0 && t == 0) off[n] = total;
}

__global__ __launch_bounds__(256) void scan2_both(int* __restrict__ wm_cnt,
                                                  int* __restrict__ wm_off,
                                                  const int* __restrict__ bsum_wm,
                                                  int* __restrict__ fs_cnt,
                                                  int* __restrict__ fs_off,
                                                  const int* __restrict__ bsum_fs) {
    __shared__ int sm[256];
    int b = blockIdx.x;
    if (b < NBW) scan2_body(wm_cnt, wm_off, bsum_wm, N_WM, E_WM, b, sm);
    else         scan2_body(fs_cnt, fs_off, bsum_fs, N_F, E_F, b - NBW, sm);
}

// ---------------------------------------------------------------------------
// aggregate (bf16): hm[i] = h[i] + sum_{j in CSR(i)} h[bucket[j]]
// one wave per node, ushort4 (8B) per lane, fp32 accumulate.
// 8-deep manual batch -> 8 independent row gathers in flight per wave.
// ---------------------------------------------------------------------------
__global__ void aggregate_kernel(const ushort_t* __restrict__ h,
                                 const int* __restrict__ off,
                                 const int* __restrict__ bucket,
                                 ushort_t* __restrict__ hm, int n) {
    int i = blockIdx.x * 4 + (threadIdx.x >> 6);
    if (i >= n) return;
    int lane = threadIdx.x & 63;
    int s0 = off[i], s1 = off[i + 1];
    const ushort4* hp = (const ushort4*)h;   // 64 ushort4 per row
    float4 acc = bf4f(hp[(size_t)i * 64 + lane]);
    int j = s0;
    // ---- 8-wide batches: load 8 indices, then 8 independent row loads ----
    for (; j + 8 <= s1; j += 8) {
        int b0 = bucket[j + 0], b1 = bucket[j + 1];
        int b2 = bucket[j + 2], b3 = bucket[j + 3];
        int b4 = bucket[j + 4], b5 = bucket[j + 5];
        int b6 = bucket[j + 6], b7 = bucket[j + 7];
        ushort4 r0 = hp[(size_t)b0 * 64 + lane];
        ushort4 r1 = hp[(size_t)b1 * 64 + lane];
        ushort4 r2 = hp[(size_t)b2 * 64 + lane];
        ushort4 r3 = hp[(size_t)b3 * 64 + lane];
        ushort4 r4 = hp[(size_t)b4 * 64 + lane];
        ushort4 r5 = hp[(size_t)b5 * 64 + lane];
        ushort4 r6 = hp[(size_t)b6 * 64 + lane];
        ushort4 r7 = hp[(size_t)b7 * 64 + lane];
        float4 v0 = bf4f(r0), v1 = bf4f(r1), v2 = bf4f(r2), v3 = bf4f(r3);
        float4 v4 = bf4f(r4), v5 = bf4f(r5), v6 = bf4f(r6), v7 = bf4f(r7);
        acc.x += v0.x + v1.x + v2.x + v3.x + v4.x + v5.x + v6.x + v7.x;
        acc.y += v0.y + v1.y + v2.y + v3.y + v4.y + v5.y + v6.y + v7.y;
        acc.z += v0.z + v1.z + v2.z + v3.z + v4.z + v5.z + v6.z + v7.z;
        acc.w += v0.w + v1.w + v2.w + v3.w + v4.w + v5.w + v6.w + v7.w;
    }
    // ---- 2-wide tail ----
    for (; j + 2 <= s1; j += 2) {
        int b0 = bucket[j + 0], b1 = bucket[j + 1];
        ushort4 r0 = hp[(size_t)b0 * 64 + lane];
        ushort4 r1 = hp[(size_t)b1 * 64 + lane];
        float4 v0 = bf4f(r0), v1 = bf4f(r1);
        acc.x += v0.x + v1.x; acc.y += v0.y + v1.y;
        acc.z += v0.z + v1.z; acc.w += v0.w + v1.w;
    }
    // ---- 1-wide tail ----
    if (j < s1) {
        int b0 = bucket[j];
        float4 v0 = bf4f(hp[(size_t)b0 * 64 + lane]);
        acc.x += v0.x; acc.y += v0.y; acc.z += v0.z; acc.w += v0.w;
    }
    ushort4 u;
    u.x = f2bf(acc.x); u.y = f2bf(acc.y); u.z = f2bf(acc.z); u.w = f2bf(acc.w);
    ((ushort4*)hm)[(size_t)i * 64 + lane] = u;
}

// ---------------------------------------------------------------------------
// tmp[i] = sum_k table[token2nodepos[i,k]+2]   (bf16 table, fp32 accumulate)
// ---------------------------------------------------------------------------
__global__ void tmp_kernel(const ushort_t* __restrict__ gemb,
                           const ushort_t* __restrict__ extra,
                           const int* __restrict__ t2np,
                           ushort_t* __restrict__ D) {
    int i = blockIdx.x * 4 + (threadIdx.x >> 6);
    int lane = threadIdx.x & 63;
    float4 s = make_float4(0.f, 0.f, 0.f, 0.f);
#pragma unroll
    for (int k = 0; k < Kc; ++k) {
        int idx = t2np[i * Kc + k] + 2;
        const ushort4* row = (idx < 2) ? (const ushort4*)(extra + (size_t)idx * Gd)
                                       : (const ushort4*)(gemb + (size_t)(idx - 2) * Gd);
        float4 v = bf4f(row[lane]);
        s.x += v.x; s.y += v.y; s.z += v.z; s.w += v.w;
    }
    ushort4 u;
    u.x = f2bf(s.x); u.y = f2bf(s.y); u.z = f2bf(s.z); u.w = f2bf(s.w);
    ((ushort4*)D)[(size_t)i * 64 + lane] = u;
}

// ---------------------------------------------------------------------------
// row gather (bf16): F[i] = E[ids[i]]
// ---------------------------------------------------------------------------
__global__ void gather_kernel(const ushort_t* __restrict__ Ein,
                              const int* __restrict__ ids,
                              ushort_t* __restrict__ F) {
    int i = blockIdx.x * 4 + (threadIdx.x >> 6);
    int lane = threadIdx.x & 63;
    ((ushort4*)F)[(size_t)i * 64 + lane] =
        ((const ushort4*)Ein)[(size_t)ids[i] * 64 + lane];
}

// ---------------------------------------------------------------------------
// bf16 MFMA GEMM, m97 structure: 128x128 tile, BK=64, global_load_lds width 16
// + bijective XCD-aware block swizzle (m204): each XCD gets a contiguous
//   chunk of linear block ids -> A row-panels fetched once per XCD, B panels
//   L2-resident.
// MODE 0: A = p0[row][k], rowlen K
// MODE 2: A = k<256 ? p0[row][k] : p1(row, k-256) rowlen 768     (tmp|text), K=1024
// MODE 3: A = k<768 ? p0 : k<1024 ? p1 : p2                      (text|tmp|temporal), K=1280
// OUTBF: 1 -> bf16 C, 0 -> fp32 C
// ---------------------------------------------------------------------------
#define TBM 128
#define TBN 128
#define TBK 64

__device__ __forceinline__ void xcd_swizzle(int& bx, int& by) {
    int gx = gridDim.x;
    int nwg = gx * gridDim.y;
    int orig = by * gx + bx;
    int q = nwg >> 3, r = nwg & 7;
    int xcd = orig & 7, loc = orig >> 3;
    int wg = (xcd < r ? xcd * (q + 1) : r * (q + 1) + (xcd - r) * q) + loc;
    bx = wg % gx;
    by = wg / gx;
}

template <int MODE, int OUTBF>
__global__ __launch_bounds__(256) void mfma_gemm(
    const ushort_t* __restrict__ p0, const ushort_t* __restrict__ p1,
    const ushort_t* __restrict__ p2, const ushort_t* __restrict__ Wt,
    const float* __restrict__ bias, void* __restrict__ Cv,
    int M, int N, int K, int relu) {
    __shared__ ushort_t As[TBM * TBK];   // [row][k], stride 64, no pad (lds-dma)
    __shared__ ushort_t Bs[TBN * TBK];   // [col][k]

    int tid  = threadIdx.x;
    int lane = tid & 63;
    int wave = tid >> 6;
    int wm = (wave >> 1) * 64, wn = (wave & 1) * 64;
    int bx = blockIdx.x, by = blockIdx.y;
    xcd_swizzle(bx, by);
    int row0 = by * TBM, col0 = bx * TBN;
    int l15 = lane & 15, l4 = lane >> 4;

    f32x4 acc[4][4];
#pragma unroll
    for (int i = 0; i < 4; ++i)
#pragma unroll
        for (int j = 0; j < 4; ++j)
            acc[i][j] = (f32x4){0.f, 0.f, 0.f, 0.f};

    for (int k0 = 0; k0 < K; k0 += TBK) {
        // ---- stage A via lds-dma: 16KB, 4 iters x (4 waves x 1KB) ----
#pragma unroll
        for (int it = 0; it < 4; ++it) {
            int eb = it * 2048 + wave * 512;   // wave-uniform elem base
            int le = eb + lane * 8;
            int r  = le >> 6;
            int kl = le & 63;
            int grow = row0 + r; if (grow > M - 1) grow = M - 1;
            int gk = k0 + kl;
            const ushort_t* gp;
            if (MODE == 0)
                gp = p0 + (size_t)grow * K + gk;
            else if (MODE == 2)
                gp = (gk < 256) ? p0 + (size_t)grow * 256 + gk
                                : p1 + (size_t)grow * 768 + (gk - 256);
            else
                gp = (gk < 768) ? p0 + (size_t)grow * 768 + gk
                   : (gk < 1024) ? p1 + (size_t)grow * 256 + (gk - 768)
                                 : p2 + (size_t)grow * 256 + (gk - 1024);
            gl2lds16(gp, &As[eb]);
        }
        // ---- stage B via lds-dma ----
#pragma unroll
        for (int it = 0; it < 4; ++it) {
            int eb = it * 2048 + wave * 512;
            int le = eb + lane * 8;
            int nl = le >> 6;
            int kl = le & 63;
            const ushort_t* gp = Wt + (size_t)(col0 + nl) * K + k0 + kl;
            gl2lds16(gp, &Bs[eb]);
        }
        __syncthreads();

#pragma unroll
        for (int ks = 0; ks < TBK; ks += 32) {
            short8 af[4], bfr[4];
#pragma unroll
            for (int mi = 0; mi < 4; ++mi)
                af[mi] = *(const short8*)&As[(wm + mi * 16 + l15) * TBK + ks + l4 * 8];
#pragma unroll
            for (int ni = 0; ni < 4; ++ni)
                bfr[ni] = *(const short8*)&Bs[(wn + ni * 16 + l15) * TBK + ks + l4 * 8];
#pragma unroll
            for (int mi = 0; mi < 4; ++mi)
#pragma unroll
                for (int ni = 0; ni < 4; ++ni)
                    acc[mi][ni] = __builtin_amdgcn_mfma_f32_16x16x32_bf16(
                        af[mi], bfr[ni], acc[mi][ni], 0, 0, 0);
        }
        __syncthreads();
    }

    // ---- epilogue: bias (+relu); C/D layout col=lane&15, row=(lane>>4)*4+reg ----
#pragma unroll
    for (int ni = 0; ni < 4; ++ni) {
        int c = col0 + wn + ni * 16 + l15;
        float bv = bias[c];
#pragma unroll
        for (int mi = 0; mi < 4; ++mi) {
#pragma unroll
            for (int r = 0; r < 4; ++r) {
                int rr = row0 + wm + mi * 16 + l4 * 4 + r;
                if (rr < M) {
                    float v = acc[mi][ni][r] + bv;
                    if (relu) v = fmaxf(v, 0.f);
                    if (OUTBF) ((ushort_t*)Cv)[(size_t)rr * N + c] = f2bf(v);
                    else       ((float*)Cv)[(size_t)rr * N + c] = v;
                }
            }
        }
    }
}

// ---------------------------------------------------------------------------
extern "C" void kernel_launch(void* const* d_in, const int* in_sizes, int n_in,
                              void* d_out, int out_size, void* d_ws, size_t ws_size,
                              hipStream_t stream) {
    const float* text    = (const float*)d_in[0];   // [16384, 768]
    const float* wm_x    = (const float*)d_in[1];   // [50000, 256]
    const int*   wm_ei   = (const int*)d_in[2];     // [2, 800000]
    const int*   t2np    = (const int*)d_in[3];     // [16384, 4]
    const int*   f_ids   = (const int*)d_in[4];     // [16384]
    const int*   f_ei    = (const int*)d_in[5];     // [2, 131072]
    const float* extra   = (const float*)d_in[6];   // [2, 256]
    const float* wm_W1   = (const float*)d_in[7];
    const float* wm_b1   = (const float*)d_in[8];
    const float* wm_W2   = (const float*)d_in[9];
    const float* wm_b2   = (const float*)d_in[10];
    const float* fs_W1   = (const float*)d_in[11];
    const float* fs_b1   = (const float*)d_in[12];
    const float* fs_W2   = (const float*)d_in[13];
    const float* fs_b2   = (const float*)d_in[14];
    const float* fc1_W   = (const float*)d_in[15];  // [1024, 256]
    const float* fc1_b   = (const float*)d_in[16];
    const float* fc3_W   = (const float*)d_in[17];  // [1280, 768]
    const float* fc3_b   = (const float*)d_in[18];
    float* out = (float*)d_out;                     // [16384, 768]

    // ---- workspace layout (bf16 = ushort) ----
    ushort_t* Xb  = (ushort_t*)d_ws;            // [50000*256] wm_x bf16 (reused: h1)
    ushort_t* Ag  = Xb + 12800000;              // [50000*256] aggregate out
    ushort_t* Gm  = Ag + 12800000;              // [50000*256] gemb (reused: F, H)
    ushort_t* Tx  = Gm + 12800000;              // [16384*768] text bf16
    ushort_t* Dt  = Tx + 12582912;              // [16384*256] tmp
    ushort_t* Ee  = Dt + 4194304;               // [16384*256] gte (reused: T)
    ushort_t* Wv  = Ee + 4194304;               // weights, transposed bf16
    ushort_t* wt_wm1 = Wv;                      //  65536
    ushort_t* wt_wm2 = wt_wm1 + 65536;          //  65536
    ushort_t* wt_fs1 = wt_wm2 + 65536;          //  65536
    ushort_t* wt_fs2 = wt_fs1 + 65536;          //  65536
    ushort_t* wt_fc1 = wt_fs2 + 65536;          //  262144
    ushort_t* wt_fc3 = wt_fc1 + 262144;         //  983040
    ushort_t* Exb    = wt_fc3 + 983040;         //  512
    int* wm_off = (int*)(Exb + 512);            // [N_WM+1]
    int* fs_off = wm_off + N_WM + 1;            // [N_F+1]
    int* wm_cnt = fs_off + N_F + 1;             // [N_WM]  (cnt arrays adjacent ->
    int* fs_cnt = wm_cnt + N_WM;                // [N_F]    single memset)
    int* wm_bkt = fs_cnt + N_F;                 // [E_WM]
    int* fs_bkt = wm_bkt + E_WM;                // [E_F]
    int* bsum_wm = fs_bkt + E_F;                // [64]
    int* bsum_fs = bsum_wm + 64;                // [16]

    ushort_t* h1 = Xb;                 // gemm1 out overwrites Xb (dead)
    ushort_t* F  = Gm;                 // gather out overwrites gemb (dead)
    ushort_t* H  = Gm + 4194304;
    ushort_t* T  = Ee;                 // fstm out overwrites Ee (dead)

    const int* wm_src = wm_ei;
    const int* wm_dst = wm_ei + E_WM;
    const int* f_src  = f_ei;
    const int* f_dst  = f_ei + E_F;

    dim3 blk(256);
    dim3 gW(Gd / TBN, (N_WM + TBM - 1) / TBM);   // 2 x 391
    dim3 gF(Gd / TBN, N_F / TBM);                // 2 x 128
    dim3 gO(PLM / TBN, N_F / TBM);               // 6 x 128

    const int nbE = (E_WM + E_F) / 256;          // 3637 (exact)

    // ===== CSR build (fused) =====
    hipMemsetAsync(wm_cnt, 0, (N_WM + N_F) * sizeof(int), stream);
    hist_both<<<nbE, blk, 0, stream>>>(wm_dst, wm_cnt, f_dst, fs_cnt);
    scan1_both<<<NBW + NBF, blk, 0, stream>>>(wm_cnt, bsum_wm, fs_cnt, bsum_fs);
    scan_bsums_both<<<1, 128, 0, stream>>>(bsum_wm, bsum_fs);
    scan2_both<<<NBW + NBF, blk, 0, stream>>>(wm_cnt, wm_off, bsum_wm,
                                              fs_cnt, fs_off, bsum_fs);
    fill_both<<<nbE, blk, 0, stream>>>(wm_src, wm_dst, wm_cnt, wm_bkt,
                                       f_src, f_dst, fs_cnt, fs_bkt);

    // ===== one-time conversions (fused) =====
    conv_all<<<30677, blk, 0, stream>>>(wm_x, text, extra,
                                        wm_W1, wm_W2, fs_W1, fs_W2, fc1_W, fc3_W,
                                        Xb, Tx, Exb,
                                        wt_wm1, wt_wm2, wt_fs1, wt_fs2,
                                        wt_fc1, wt_fc3);

    // ===== WM layer 1 =====
    aggregate_kernel<<<(N_WM + 3) / 4, blk, 0, stream>>>(Xb, wm_off, wm_bkt, Ag, N_WM);
    mfma_gemm<0, 1><<<gW, blk, 0, stream>>>(Ag, nullptr, nullptr, wt_wm1, wm_b1,
                                            h1, N_WM, Gd, Gd, 1);
    // ===== WM layer 2 =====
    aggregate_kernel<<<(N_WM + 3) / 4, blk, 0, stream>>>(h1, wm_off, wm_bkt, Ag, N_WM);
    mfma_gemm<0, 1><<<gW, blk, 0, stream>>>(Ag, nullptr, nullptr, wt_wm2, wm_b2,
                                            Gm, N_WM, Gd, Gd, 1);
    // ===== tmp =====
    tmp_kernel<<<N_F / 4, blk, 0, stream>>>(Gm, Exb, t2np, Dt);
    // ===== fc1: Ee = concat(tmp, text) @ fc1_W + b =====
    mfma_gemm<2, 1><<<gF, blk, 0, stream>>>(Dt, Tx, nullptr, wt_fc1, fc1_b,
                                            Ee, N_F, Gd, Gd + PLM, 0);
    // ===== FSTM gather =====
    gather_kernel<<<N_F / 4, blk, 0, stream>>>(Ee, f_ids, F);
    // ===== FSTM layer 1 =====
    aggregate_kernel<<<N_F / 4, blk, 0, stream>>>(F, fs_off, fs_bkt, Ag, N_F);
    mfma_gemm<0, 1><<<gF, blk, 0, stream>>>(Ag, nullptr, nullptr, wt_fs1, fs_b1,
                                            H, N_F, Gd, Gd, 1);
    // ===== FSTM layer 2 =====
    aggregate_kernel<<<N_F / 4, blk, 0, stream>>>(H, fs_off, fs_bkt, Ag, N_F);
    mfma_gemm<0, 1><<<gF, blk, 0, stream>>>(Ag, nullptr, nullptr, wt_fs2, fs_b2,
                                            T, N_F, Gd, Gd, 1);
    // ===== fc3: out = concat(text, tmp, temporal) @ fc3_W + b (fp32 out) =====
    mfma_gemm<3, 0><<<gO, blk, 0, stream>>>(Tx, Dt, T, wt_fc3, fc3_b,
                                            out, N_F, PLM, PLM + 2 * Gd, 0);
}

// Round 3
// 556.019 us; speedup vs baseline: 1.3584x; 1.1408x over previous
//
#include <hip/hip_runtime.h>

// Problem constants (match reference)
#define Bsz 8
#define Ssz 2048
#define PLM 768
#define Gd  256
#define N_WM 50000
#define E_WM 800000
#define N_F  16384   // B*S
#define E_F  131072
#define Kc   4

typedef unsigned short ushort_t;
typedef short short8 __attribute__((ext_vector_type(8)));
typedef float f32x4 __attribute__((ext_vector_type(4)));

// RNE float -> bf16 bits
__device__ __forceinline__ ushort_t f2bf(float f) {
    union { float f; unsigned int u; } v; v.f = f;
    unsigned int r = (v.u + 0x7fffu + ((v.u >> 16) & 1u)) >> 16;
    return (ushort_t)r;
}
__device__ __forceinline__ float bf2f(ushort_t b) {
    union { unsigned int u; float f; } v; v.u = ((unsigned int)b) << 16;
    return v.f;
}
__device__ __forceinline__ float4 bf4f(ushort4 u) {
    return make_float4(bf2f(u.x), bf2f(u.y), bf2f(u.z), bf2f(u.w));
}

// async global->LDS, 16B per lane; LDS dest must be wave-uniform base
__device__ __forceinline__ void gl2lds16(const ushort_t* g, ushort_t* l) {
    __builtin_amdgcn_global_load_lds(
        (const __attribute__((address_space(1))) unsigned int*)g,
        (__attribute__((address_space(3))) unsigned int*)l, 16, 0, 0);
}

// ---------------------------------------------------------------------------
// fused one-time conversions: cvt wm_x, cvt text, cvt extra, 6 weight
// transposes — one dispatch.
// ---------------------------------------------------------------------------
__device__ __forceinline__ void cvt4(const float* __restrict__ in,
                                     ushort_t* __restrict__ out, int i, int n4) {
    if (i < n4) {
        float4 v = ((const float4*)in)[i];
        ushort4 u;
        u.x = f2bf(v.x); u.y = f2bf(v.y); u.z = f2bf(v.z); u.w = f2bf(v.w);
        ((ushort4*)out)[i] = u;
    }
}
__device__ __forceinline__ void wtx(const float* __restrict__ W,
                                    ushort_t* __restrict__ Wt, int K, int N, int idx) {
    if (idx < N * K) {
        int n = idx / K, k = idx % K;
        Wt[idx] = f2bf(W[(size_t)k * N + n]);
    }
}

// block ranges: 12500 (wm_x) | 12288 (text) | 1 (extra) | 256x4 (256^2 wt)
//             | 1024 (fc1 wt) | 3840 (fc3 wt)   => total 30677 blocks
__global__ void conv_all(const float* __restrict__ wm_x, const float* __restrict__ text,
                         const float* __restrict__ extra,
                         const float* __restrict__ W1, const float* __restrict__ W2,
                         const float* __restrict__ W3, const float* __restrict__ W4,
                         const float* __restrict__ W5, const float* __restrict__ W6,
                         ushort_t* __restrict__ Xb, ushort_t* __restrict__ Tx,
                         ushort_t* __restrict__ Exb,
                         ushort_t* __restrict__ T1, ushort_t* __restrict__ T2,
                         ushort_t* __restrict__ T3, ushort_t* __restrict__ T4,
                         ushort_t* __restrict__ T5, ushort_t* __restrict__ T6) {
    int b = blockIdx.x, t = threadIdx.x;
    if (b < 12500) { cvt4(wm_x, Xb, b * 256 + t, 3200000); return; }
    b -= 12500;
    if (b < 12288) { cvt4(text, Tx, b * 256 + t, 3145728); return; }
    b -= 12288;
    if (b < 1) { cvt4(extra, Exb, t, 128); return; }
    b -= 1;
    if (b < 256) { wtx(W1, T1, 256, 256, b * 256 + t); return; }
    b -= 256;
    if (b < 256) { wtx(W2, T2, 256, 256, b * 256 + t); return; }
    b -= 256;
    if (b < 256) { wtx(W3, T3, 256, 256, b * 256 + t); return; }
    b -= 256;
    if (b < 256) { wtx(W4, T4, 256, 256, b * 256 + t); return; }
    b -= 256;
    if (b < 1024) { wtx(W5, T5, 1024, 256, b * 256 + t); return; }
    b -= 1024;
    wtx(W6, T6, 1280, 768, b * 256 + t);
}

// ---------------------------------------------------------------------------
// CSR build v2: 2-level LDS-atomic counting sort. NO global atomics.
//   p1 : per-slice coarse histogram (256 buckets) -> C[p][256]  (coalesced)
//   p2a: per-bucket column exclusive scan of C; bucket totals -> BT[256]
//   p2b: scan BT -> BStart[257]
//   p3 : replay slice, LDS cursors (C[p][.]+BStart) -> SE[pos]=(src,dst) int2
//   p4 : per coarse bucket: fine LDS count+scan+scatter -> off[], bkt[]
// Coarse bucket: WM dst>>8 (196 used of 256), FSTM dst>>6 (256 exact).
// ---------------------------------------------------------------------------
#define WM_P 512
#define WM_CH 1563          // ceil(E_WM/WM_P); 512*1563 >= 800000
#define WM_SHIFT 8
#define FS_P 128
#define FS_CH 1024          // E_F/FS_P exact
#define FS_SHIFT 6

__global__ __launch_bounds__(256) void csr_p1(const int* __restrict__ wm_dst,
                                              const int* __restrict__ f_dst,
                                              int* __restrict__ Cwm,
                                              int* __restrict__ Cfs) {
    __shared__ int hist[256];
    int b = blockIdx.x, t = threadIdx.x;
    hist[t] = 0; __syncthreads();
    if (b < WM_P) {
        int e0 = b * WM_CH, e1 = e0 + WM_CH; if (e1 > E_WM) e1 = E_WM;
        for (int e = e0 + t; e < e1; e += 256)
            atomicAdd(&hist[wm_dst[e] >> WM_SHIFT], 1);
        __syncthreads();
        Cwm[b * 256 + t] = hist[t];
    } else {
        int p = b - WM_P;
        int e0 = p * FS_CH, e1 = e0 + FS_CH;
        for (int e = e0 + t; e < e1; e += 256)
            atomicAdd(&hist[f_dst[e] >> FS_SHIFT], 1);
        __syncthreads();
        Cfs[p * 256 + t] = hist[t];
    }
}

// per-bucket column exclusive scan (order within bucket: p = 2t, 2t+1).
// 512 blocks: 0..255 = WM buckets, 256..511 = FS buckets.
__global__ __launch_bounds__(256) void csr_p2a(int* __restrict__ Cwm, int* __restrict__ BTwm,
                                               int* __restrict__ Cfs, int* __restrict__ BTfs) {
    __shared__ int sm[256];
    int b = blockIdx.x, t = threadIdx.x;
    int* C; int* BT; int P; int bk;
    if (b < 256) { C = Cwm; BT = BTwm; P = WM_P; bk = b; }
    else         { C = Cfs; BT = BTfs; P = FS_P; bk = b - 256; }
    int half = P >> 1;    // threads 0..half-1 active
    int v0 = 0, v1 = 0;
    if (t < half) { v0 = C[(2 * t) * 256 + bk]; v1 = C[(2 * t + 1) * 256 + bk]; }
    int s = v0 + v1;
    sm[t] = s; __syncthreads();
#pragma unroll
    for (int st = 1; st < 256; st <<= 1) {
        int x = (t >= st) ? sm[t - st] : 0;
        __syncthreads();
        sm[t] += x;
        __syncthreads();
    }
    int ex = sm[t] - s;
    if (t < half) {
        C[(2 * t) * 256 + bk] = ex;
        C[(2 * t + 1) * 256 + bk] = ex + v0;
    }
    if (t == 255) BT[bk] = sm[255];
}

// scan bucket totals -> BStart[257]. 2 blocks: 0 = WM, 1 = FS.
__global__ __launch_bounds__(256) void csr_p2b(const int* __restrict__ BTwm,
                                               int* __restrict__ BSwm,
                                               const int* __restrict__ BTfs,
                                               int* __restrict__ BSfs) {
    __shared__ int sm[256];
    int t = threadIdx.x;
    const int* BT = blockIdx.x ? BTfs : BTwm;
    int* BS = blockIdx.x ? BSfs : BSwm;
    int E = blockIdx.x ? E_F : E_WM;
    int v = BT[t];
    sm[t] = v; __syncthreads();
#pragma unroll
    for (int st = 1; st < 256; st <<= 1) {
        int x = (t >= st) ? sm[t - st] : 0;
        __syncthreads();
        sm[t] += x;
        __syncthreads();
    }
    BS[t] = sm[t] - v;
    if (t == 255) BS[256] = E;
}

// coarse scatter: (src,dst) int2 into bucket-major SE via LDS cursors
__global__ __launch_bounds__(256) void csr_p3(const int* __restrict__ wm_src,
                                              const int* __restrict__ wm_dst,
                                              const int* __restrict__ Cwm,
                                              const int* __restrict__ BSwm,
                                              int2* __restrict__ SEwm,
                                              const int* __restrict__ f_src,
                                              const int* __restrict__ f_dst,
                                              const int* __restrict__ Cfs,
                                              const int* __restrict__ BSfs,
                                              int2* __restrict__ SEfs) {
    __shared__ int cur[256];
    int b = blockIdx.x, t = threadIdx.x;
    if (b < WM_P) {
        cur[t] = Cwm[b * 256 + t] + BSwm[t];
        __syncthreads();
        int e0 = b * WM_CH, e1 = e0 + WM_CH; if (e1 > E_WM) e1 = E_WM;
        for (int e = e0 + t; e < e1; e += 256) {
            int d = wm_dst[e], s = wm_src[e];
            int pos = atomicAdd(&cur[d >> WM_SHIFT], 1);
            SEwm[pos] = make_int2(s, d);
        }
    } else {
        int p = b - WM_P;
        cur[t] = Cfs[p * 256 + t] + BSfs[t];
        __syncthreads();
        int e0 = p * FS_CH, e1 = e0 + FS_CH;
        for (int e = e0 + t; e < e1; e += 256) {
            int d = f_dst[e], s = f_src[e];
            int pos = atomicAdd(&cur[d >> FS_SHIFT], 1);
            SEfs[pos] = make_int2(s, d);
        }
    }
}

// fine CSR within each coarse bucket. 512 blocks: 0..255 WM, 256..511 FS.
__global__ __launch_bounds__(256) void csr_p4(const int2* __restrict__ SEwm,
                                              const int* __restrict__ BSwm,
                                              int* __restrict__ wm_off,
                                              int* __restrict__ wm_bkt,
                                              const int2* __restrict__ SEfs,
                                              const int* __restrict__ BSfs,
                                              int* __restrict__ fs_off,
                                              int* __restrict__ fs_bkt) {
    __shared__ int cnt[256];
    __shared__ int sm[256];
    int ob = blockIdx.x, t = threadIdx.x;
    const int2* SE; const int* BS; int* off; int* bkt;
    int b, nb0, n, E, bw;
    if (ob < 256) { SE = SEwm; BS = BSwm; off = wm_off; bkt = wm_bkt;
                    b = ob; nb0 = b << WM_SHIFT; n = N_WM; E = E_WM; bw = 256; }
    else          { SE = SEfs; BS = BSfs; off = fs_off; bkt = fs_bkt;
                    b = ob - 256; nb0 = b << FS_SHIFT; n = N_F; E = E_F; bw = 64; }
    int e0 = BS[b], e1 = BS[b + 1];
    cnt[t] = 0; __syncthreads();
    for (int e = e0 + t; e < e1; e += 256)
        atomicAdd(&cnt[SE[e].y - nb0], 1);
    __syncthreads();
    int v = cnt[t];
    sm[t] = v; __syncthreads();
#pragma unroll
    for (int st = 1; st < 256; st <<= 1) {
        int x = (t >= st) ? sm[t - st] : 0;
        __syncthreads();
        sm[t] += x;
        __syncthreads();
    }
    int ex = sm[t] - v;
    if (t < bw && nb0 + t < n) off[nb0 + t] = e0 + ex;
    if (b == 0 && t == 0) off[n] = E;
    __syncthreads();
    cnt[t] = e0 + ex;        // cursors
    __syncthreads();
    for (int e = e0 + t; e < e1; e += 256) {
        int2 sd = SE[e];
        int pos = atomicAdd(&cnt[sd.y - nb0], 1);
        bkt[pos] = sd.x;
    }
}

// ---------------------------------------------------------------------------
// aggregate (bf16): hm[i] = h[i] + sum_{j in CSR(i)} h[bucket[j]]
// one wave per node, ushort4 (8B) per lane, fp32 accumulate.
// 8-deep manual batch -> 8 independent row gathers in flight per wave.
// ---------------------------------------------------------------------------
__global__ void aggregate_kernel(const ushort_t* __restrict__ h,
                                 const int* __restrict__ off,
                                 const int* __restrict__ bucket,
                                 ushort_t* __restrict__ hm, int n) {
    int i = blockIdx.x * 4 + (threadIdx.x >> 6);
    if (i >= n) return;
    int lane = threadIdx.x & 63;
    int s0 = off[i], s1 = off[i + 1];
    const ushort4* hp = (const ushort4*)h;   // 64 ushort4 per row
    float4 acc = bf4f(hp[(size_t)i * 64 + lane]);
    int j = s0;
    // ---- 8-wide batches: load 8 indices, then 8 independent row loads ----
    for (; j + 8 <= s1; j += 8) {
        int b0 = bucket[j + 0], b1 = bucket[j + 1];
        int b2 = bucket[j + 2], b3 = bucket[j + 3];
        int b4 = bucket[j + 4], b5 = bucket[j + 5];
        int b6 = bucket[j + 6], b7 = bucket[j + 7];
        ushort4 r0 = hp[(size_t)b0 * 64 + lane];
        ushort4 r1 = hp[(size_t)b1 * 64 + lane];
        ushort4 r2 = hp[(size_t)b2 * 64 + lane];
        ushort4 r3 = hp[(size_t)b3 * 64 + lane];
        ushort4 r4 = hp[(size_t)b4 * 64 + lane];
        ushort4 r5 = hp[(size_t)b5 * 64 + lane];
        ushort4 r6 = hp[(size_t)b6 * 64 + lane];
        ushort4 r7 = hp[(size_t)b7 * 64 + lane];
        float4 v0 = bf4f(r0), v1 = bf4f(r1), v2 = bf4f(r2), v3 = bf4f(r3);
        float4 v4 = bf4f(r4), v5 = bf4f(r5), v6 = bf4f(r6), v7 = bf4f(r7);
        acc.x += v0.x + v1.x + v2.x + v3.x + v4.x + v5.x + v6.x + v7.x;
        acc.y += v0.y + v1.y + v2.y + v3.y + v4.y + v5.y + v6.y + v7.y;
        acc.z += v0.z + v1.z + v2.z + v3.z + v4.z + v5.z + v6.z + v7.z;
        acc.w += v0.w + v1.w + v2.w + v3.w + v4.w + v5.w + v6.w + v7.w;
    }
    // ---- 2-wide tail ----
    for (; j + 2 <= s1; j += 2) {
        int b0 = bucket[j + 0], b1 = bucket[j + 1];
        ushort4 r0 = hp[(size_t)b0 * 64 + lane];
        ushort4 r1 = hp[(size_t)b1 * 64 + lane];
        float4 v0 = bf4f(r0), v1 = bf4f(r1);
        acc.x += v0.x + v1.x; acc.y += v0.y + v1.y;
        acc.z += v0.z + v1.z; acc.w += v0.w + v1.w;
    }
    // ---- 1-wide tail ----
    if (j < s1) {
        int b0 = bucket[j];
        float4 v0 = bf4f(hp[(size_t)b0 * 64 + lane]);
        acc.x += v0.x; acc.y += v0.y; acc.z += v0.z; acc.w += v0.w;
    }
    ushort4 u;
    u.x = f2bf(acc.x); u.y = f2bf(acc.y); u.z = f2bf(acc.z); u.w = f2bf(acc.w);
    ((ushort4*)hm)[(size_t)i * 64 + lane] = u;
}

// ---------------------------------------------------------------------------
// tmp[i] = sum_k table[token2nodepos[i,k]+2]   (bf16 table, fp32 accumulate)
// ---------------------------------------------------------------------------
__global__ void tmp_kernel(const ushort_t* __restrict__ gemb,
                           const ushort_t* __restrict__ extra,
                           const int* __restrict__ t2np,
                           ushort_t* __restrict__ D) {
    int i = blockIdx.x * 4 + (threadIdx.x >> 6);
    int lane = threadIdx.x & 63;
    float4 s = make_float4(0.f, 0.f, 0.f, 0.f);
#pragma unroll
    for (int k = 0; k < Kc; ++k) {
        int idx = t2np[i * Kc + k] + 2;
        const ushort4* row = (idx < 2) ? (const ushort4*)(extra + (size_t)idx * Gd)
                                       : (const ushort4*)(gemb + (size_t)(idx - 2) * Gd);
        float4 v = bf4f(row[lane]);
        s.x += v.x; s.y += v.y; s.z += v.z; s.w += v.w;
    }
    ushort4 u;
    u.x = f2bf(s.x); u.y = f2bf(s.y); u.z = f2bf(s.z); u.w = f2bf(s.w);
    ((ushort4*)D)[(size_t)i * 64 + lane] = u;
}

// ---------------------------------------------------------------------------
// row gather (bf16): F[i] = E[ids[i]]
// ---------------------------------------------------------------------------
__global__ void gather_kernel(const ushort_t* __restrict__ Ein,
                              const int* __restrict__ ids,
                              ushort_t* __restrict__ F) {
    int i = blockIdx.x * 4 + (threadIdx.x >> 6);
    int lane = threadIdx.x & 63;
    ((ushort4*)F)[(size_t)i * 64 + lane] =
        ((const ushort4*)Ein)[(size_t)ids[i] * 64 + lane];
}

// ---------------------------------------------------------------------------
// bf16 MFMA GEMM, m97 structure: 128x128 tile, BK=64, global_load_lds width 16
// + bijective XCD-aware block swizzle (m204).
// MODE 0: A = p0[row][k], rowlen K
// MODE 2: A = k<256 ? p0[row][k] : p1(row, k-256) rowlen 768     (tmp|text), K=1024
// MODE 3: A = k<768 ? p0 : k<1024 ? p1 : p2                      (text|tmp|temporal), K=1280
// OUTBF: 1 -> bf16 C, 0 -> fp32 C
// ---------------------------------------------------------------------------
#define TBM 128
#define TBN 128
#define TBK 64

__device__ __forceinline__ void xcd_swizzle(int& bx, int& by) {
    int gx = gridDim.x;
    int nwg = gx * gridDim.y;
    int orig = by * gx + bx;
    int q = nwg >> 3, r = nwg & 7;
    int xcd = orig & 7, loc = orig >> 3;
    int wg = (xcd < r ? xcd * (q + 1) : r * (q + 1) + (xcd - r) * q) + loc;
    bx = wg % gx;
    by = wg / gx;
}

template <int MODE, int OUTBF>
__global__ __launch_bounds__(256) void mfma_gemm(
    const ushort_t* __restrict__ p0, const ushort_t* __restrict__ p1,
    const ushort_t* __restrict__ p2, const ushort_t* __restrict__ Wt,
    const float* __restrict__ bias, void* __restrict__ Cv,
    int M, int N, int K, int relu) {
    __shared__ ushort_t As[TBM * TBK];   // [row][k], stride 64, no pad (lds-dma)
    __shared__ ushort_t Bs[TBN * TBK];   // [col][k]

    int tid  = threadIdx.x;
    int lane = tid & 63;
    int wave = tid >> 6;
    int wm = (wave >> 1) * 64, wn = (wave & 1) * 64;
    int bx = blockIdx.x, by = blockIdx.y;
    xcd_swizzle(bx, by);
    int row0 = by * TBM, col0 = bx * TBN;
    int l15 = lane & 15, l4 = lane >> 4;

    f32x4 acc[4][4];
#pragma unroll
    for (int i = 0; i < 4; ++i)
#pragma unroll
        for (int j = 0; j < 4; ++j)
            acc[i][j] = (f32x4){0.f, 0.f, 0.f, 0.f};

    for (int k0 = 0; k0 < K; k0 += TBK) {
        // ---- stage A via lds-dma: 16KB, 4 iters x (4 waves x 1KB) ----
#pragma unroll
        for (int it = 0; it < 4; ++it) {
            int eb = it * 2048 + wave * 512;   // wave-uniform elem base
            int le = eb + lane * 8;
            int r  = le >> 6;
            int kl = le & 63;
            int grow = row0 + r; if (grow > M - 1) grow = M - 1;
            int gk = k0 + kl;
            const ushort_t* gp;
            if (MODE == 0)
                gp = p0 + (size_t)grow * K + gk;
            else if (MODE == 2)
                gp = (gk < 256) ? p0 + (size_t)grow * 256 + gk
                                : p1 + (size_t)grow * 768 + (gk - 256);
            else
                gp = (gk < 768) ? p0 + (size_t)grow * 768 + gk
                   : (gk < 1024) ? p1 + (size_t)grow * 256 + (gk - 768)
                                 : p2 + (size_t)grow * 256 + (gk - 1024);
            gl2lds16(gp, &As[eb]);
        }
        // ---- stage B via lds-dma ----
#pragma unroll
        for (int it = 0; it < 4; ++it) {
            int eb = it * 2048 + wave * 512;
            int le = eb + lane * 8;
            int nl = le >> 6;
            int kl = le & 63;
            const ushort_t* gp = Wt + (size_t)(col0 + nl) * K + k0 + kl;
            gl2lds16(gp, &Bs[eb]);
        }
        __syncthreads();

#pragma unroll
        for (int ks = 0; ks < TBK; ks += 32) {
            short8 af[4], bfr[4];
#pragma unroll
            for (int mi = 0; mi < 4; ++mi)
                af[mi] = *(const short8*)&As[(wm + mi * 16 + l15) * TBK + ks + l4 * 8];
#pragma unroll
            for (int ni = 0; ni < 4; ++ni)
                bfr[ni] = *(const short8*)&Bs[(wn + ni * 16 + l15) * TBK + ks + l4 * 8];
#pragma unroll
            for (int mi = 0; mi < 4; ++mi)
#pragma unroll
                for (int ni = 0; ni < 4; ++ni)
                    acc[mi][ni] = __builtin_amdgcn_mfma_f32_16x16x32_bf16(
                        af[mi], bfr[ni], acc[mi][ni], 0, 0, 0);
        }
        __syncthreads();
    }

    // ---- epilogue: bias (+relu); C/D layout col=lane&15, row=(lane>>4)*4+reg ----
#pragma unroll
    for (int ni = 0; ni < 4; ++ni) {
        int c = col0 + wn + ni * 16 + l15;
        float bv = bias[c];
#pragma unroll
        for (int mi = 0; mi < 4; ++mi) {
#pragma unroll
            for (int r = 0; r < 4; ++r) {
                int rr = row0 + wm + mi * 16 + l4 * 4 + r;
                if (rr < M) {
                    float v = acc[mi][ni][r] + bv;
                    if (relu) v = fmaxf(v, 0.f);
                    if (OUTBF) ((ushort_t*)Cv)[(size_t)rr * N + c] = f2bf(v);
                    else       ((float*)Cv)[(size_t)rr * N + c] = v;
                }
            }
        }
    }
}

// ---------------------------------------------------------------------------
extern "C" void kernel_launch(void* const* d_in, const int* in_sizes, int n_in,
                              void* d_out, int out_size, void* d_ws, size_t ws_size,
                              hipStream_t stream) {
    const float* text    = (const float*)d_in[0];   // [16384, 768]
    const float* wm_x    = (const float*)d_in[1];   // [50000, 256]
    const int*   wm_ei   = (const int*)d_in[2];     // [2, 800000]
    const int*   t2np    = (const int*)d_in[3];     // [16384, 4]
    const int*   f_ids   = (const int*)d_in[4];     // [16384]
    const int*   f_ei    = (const int*)d_in[5];     // [2, 131072]
    const float* extra   = (const float*)d_in[6];   // [2, 256]
    const float* wm_W1   = (const float*)d_in[7];
    const float* wm_b1   = (const float*)d_in[8];
    const float* wm_W2   = (const float*)d_in[9];
    const float* wm_b2   = (const float*)d_in[10];
    const float* fs_W1   = (const float*)d_in[11];
    const float* fs_b1   = (const float*)d_in[12];
    const float* fs_W2   = (const float*)d_in[13];
    const float* fs_b2   = (const float*)d_in[14];
    const float* fc1_W   = (const float*)d_in[15];  // [1024, 256]
    const float* fc1_b   = (const float*)d_in[16];
    const float* fc3_W   = (const float*)d_in[17];  // [1280, 768]
    const float* fc3_b   = (const float*)d_in[18];
    float* out = (float*)d_out;                     // [16384, 768]

    // ---- workspace layout (bf16 = ushort) ----
    ushort_t* Xb  = (ushort_t*)d_ws;            // [50000*256] wm_x bf16 (reused: h1)
    ushort_t* Ag  = Xb + 12800000;              // [50000*256] aggregate out
    ushort_t* Gm  = Ag + 12800000;              // [50000*256] gemb (reused: F, H)
    ushort_t* Tx  = Gm + 12800000;              // [16384*768] text bf16
    ushort_t* Dt  = Tx + 12582912;              // [16384*256] tmp
    ushort_t* Ee  = Dt + 4194304;               // [16384*256] gte (reused: T)
    ushort_t* Wv  = Ee + 4194304;               // weights, transposed bf16
    ushort_t* wt_wm1 = Wv;                      //  65536
    ushort_t* wt_wm2 = wt_wm1 + 65536;          //  65536
    ushort_t* wt_fs1 = wt_wm2 + 65536;          //  65536
    ushort_t* wt_fs2 = wt_fs1 + 65536;          //  65536
    ushort_t* wt_fc1 = wt_fs2 + 65536;          //  262144
    ushort_t* wt_fc3 = wt_fc1 + 262144;         //  983040
    ushort_t* Exb    = wt_fc3 + 983040;         //  512
    // persistent CSR outputs
    int* wm_off = (int*)(Exb + 512);            // [N_WM+1]
    int* fs_off = wm_off + N_WM + 1;            // [N_F+1]
    int* wm_bkt = fs_off + N_F + 1;             // [E_WM]
    int* fs_bkt = wm_bkt + E_WM;                // [E_F]
    // CSR-build scratch overlaid on Ag (dead until first aggregate)
    int2* SEwm = (int2*)Ag;                     // [E_WM] int2 (6.4MB)
    int2* SEfs = SEwm + E_WM;                   // [E_F]  int2 (1.05MB)
    int*  Cwm  = (int*)(SEfs + E_F);            // [WM_P*256]
    int*  Cfs  = Cwm + WM_P * 256;              // [FS_P*256]
    int*  BTwm = Cfs + FS_P * 256;              // [256]
    int*  BTfs = BTwm + 256;                    // [256]
    int*  BSwm = BTfs + 256;                    // [257]
    int*  BSfs = BSwm + 257;                    // [257]

    ushort_t* h1 = Xb;                 // gemm1 out overwrites Xb (dead)
    ushort_t* F  = Gm;                 // gather out overwrites gemb (dead)
    ushort_t* H  = Gm + 4194304;
    ushort_t* T  = Ee;                 // fstm out overwrites Ee (dead)

    const int* wm_src = wm_ei;
    const int* wm_dst = wm_ei + E_WM;
    const int* f_src  = f_ei;
    const int* f_dst  = f_ei + E_F;

    dim3 blk(256);
    dim3 gW(Gd / TBN, (N_WM + TBM - 1) / TBM);   // 2 x 391
    dim3 gF(Gd / TBN, N_F / TBM);                // 2 x 128
    dim3 gO(PLM / TBN, N_F / TBM);               // 6 x 128

    // ===== CSR build (counting sort, LDS atomics only) =====
    csr_p1<<<WM_P + FS_P, blk, 0, stream>>>(wm_dst, f_dst, Cwm, Cfs);
    csr_p2a<<<512, blk, 0, stream>>>(Cwm, BTwm, Cfs, BTfs);
    csr_p2b<<<2, blk, 0, stream>>>(BTwm, BSwm, BTfs, BSfs);
    csr_p3<<<WM_P + FS_P, blk, 0, stream>>>(wm_src, wm_dst, Cwm, BSwm, SEwm,
                                            f_src, f_dst, Cfs, BSfs, SEfs);
    csr_p4<<<512, blk, 0, stream>>>(SEwm, BSwm, wm_off, wm_bkt,
                                    SEfs, BSfs, fs_off, fs_bkt);

    // ===== one-time conversions (fused) =====
    conv_all<<<30677, blk, 0, stream>>>(wm_x, text, extra,
                                        wm_W1, wm_W2, fs_W1, fs_W2, fc1_W, fc3_W,
                                        Xb, Tx, Exb,
                                        wt_wm1, wt_wm2, wt_fs1, wt_fs2,
                                        wt_fc1, wt_fc3);

    // ===== WM layer 1 =====
    aggregate_kernel<<<(N_WM + 3) / 4, blk, 0, stream>>>(Xb, wm_off, wm_bkt, Ag, N_WM);
    mfma_gemm<0, 1><<<gW, blk, 0, stream>>>(Ag, nullptr, nullptr, wt_wm1, wm_b1,
                                            h1, N_WM, Gd, Gd, 1);
    // ===== WM layer 2 =====
    aggregate_kernel<<<(N_WM + 3) / 4, blk, 0, stream>>>(h1, wm_off, wm_bkt, Ag, N_WM);
    mfma_gemm<0, 1><<<gW, blk, 0, stream>>>(Ag, nullptr, nullptr, wt_wm2, wm_b2,
                                            Gm, N_WM, Gd, Gd, 1);
    // ===== tmp =====
    tmp_kernel<<<N_F / 4, blk, 0, stream>>>(Gm, Exb, t2np, Dt);
    // ===== fc1: Ee = concat(tmp, text) @ fc1_W + b =====
    mfma_gemm<2, 1><<<gF, blk, 0, stream>>>(Dt, Tx, nullptr, wt_fc1, fc1_b,
                                            Ee, N_F, Gd, Gd + PLM, 0);
    // ===== FSTM gather =====
    gather_kernel<<<N_F / 4, blk, 0, stream>>>(Ee, f_ids, F);
    // ===== FSTM layer 1 =====
    aggregate_kernel<<<N_F / 4, blk, 0, stream>>>(F, fs_off, fs_bkt, Ag, N_F);
    mfma_gemm<0, 1><<<gF, blk, 0, stream>>>(Ag, nullptr, nullptr, wt_fs1, fs_b1,
                                            H, N_F, Gd, Gd, 1);
    // ===== FSTM layer 2 =====
    aggregate_kernel<<<N_F / 4, blk, 0, stream>>>(H, fs_off, fs_bkt, Ag, N_F);
    mfma_gemm<0, 1><<<gF, blk, 0, stream>>>(Ag, nullptr, nullptr, wt_fs2, fs_b2,
                                            T, N_F, Gd, Gd, 1);
    // ===== fc3: out = concat(text, tmp, temporal) @ fc3_W + b (fp32 out) =====
    mfma_gemm<3, 0><<<gO, blk, 0, stream>>>(Tx, Dt, T, wt_fc3, fc3_b,
                                            out, N_F, PLM, PLM + 2 * Gd, 0);
}

// Round 4
// 533.504 us; speedup vs baseline: 1.4158x; 1.0422x over previous
//
#include <hip/hip_runtime.h>

// Problem constants (match reference)
#define Bsz 8
#define Ssz 2048
#define PLM 768
#define Gd  256
#define N_WM 50000
#define E_WM 800000
#define N_F  16384   // B*S
#define E_F  131072
#define Kc   4

typedef unsigned short ushort_t;
typedef short short8 __attribute__((ext_vector_type(8)));
typedef float f32x4 __attribute__((ext_vector_type(4)));

// RNE float -> bf16 bits
__device__ __forceinline__ ushort_t f2bf(float f) {
    union { float f; unsigned int u; } v; v.f = f;
    unsigned int r = (v.u + 0x7fffu + ((v.u >> 16) & 1u)) >> 16;
    return (ushort_t)r;
}
__device__ __forceinline__ float bf2f(ushort_t b) {
    union { unsigned int u; float f; } v; v.u = ((unsigned int)b) << 16;
    return v.f;
}
__device__ __forceinline__ float4 bf4f(ushort4 u) {
    return make_float4(bf2f(u.x), bf2f(u.y), bf2f(u.z), bf2f(u.w));
}

// async global->LDS, 16B per lane; LDS dest must be wave-uniform base
__device__ __forceinline__ void gl2lds16(const ushort_t* g, ushort_t* l) {
    __builtin_amdgcn_global_load_lds(
        (const __attribute__((address_space(1))) unsigned int*)g,
        (__attribute__((address_space(3))) unsigned int*)l, 16, 0, 0);
}

// ---------------------------------------------------------------------------
// fused one-time conversions: cvt wm_x, cvt text, cvt extra, 6 weight
// transposes (64x64 LDS-tiled: both global sides coalesced) — one dispatch.
// ---------------------------------------------------------------------------
__device__ __forceinline__ void cvt4(const float* __restrict__ in,
                                     ushort_t* __restrict__ out, int i, int n4) {
    if (i < n4) {
        float4 v = ((const float4*)in)[i];
        ushort4 u;
        u.x = f2bf(v.x); u.y = f2bf(v.y); u.z = f2bf(v.z); u.w = f2bf(v.w);
        ((ushort4*)out)[i] = u;
    }
}

// one 64x64 tile of W[k][n] -> Wt[n][k], via padded LDS
__device__ __forceinline__ void wtx_tile(const float* __restrict__ W,
                                         ushort_t* __restrict__ Wt,
                                         int K, int N, int tile,
                                         ushort_t (*sm)[65]) {
    int kt = K >> 6;
    int k0 = (tile % kt) << 6;
    int n0 = (tile / kt) << 6;
    int t = threadIdx.x;
    int tr = t >> 6, tc = t & 63;
#pragma unroll
    for (int p = 0; p < 16; ++p) {
        int k = p * 4 + tr;
        sm[k][tc] = f2bf(W[(size_t)(k0 + k) * N + n0 + tc]);
    }
    __syncthreads();
#pragma unroll
    for (int p = 0; p < 16; ++p) {
        int n = p * 4 + tr;
        Wt[(size_t)(n0 + n) * K + k0 + tc] = sm[tc][n];
    }
}

// block ranges: 12500 cvt wm_x | 12288 cvt text | 1 extra
//             | 16 wm1 | 16 wm2 | 16 fs1 | 16 fs2 | 64 fc1 | 240 fc3
// total 25157 blocks
__global__ void conv_all(const float* __restrict__ wm_x, const float* __restrict__ text,
                         const float* __restrict__ extra,
                         const float* __restrict__ W1, const float* __restrict__ W2,
                         const float* __restrict__ W3, const float* __restrict__ W4,
                         const float* __restrict__ W5, const float* __restrict__ W6,
                         ushort_t* __restrict__ Xb, ushort_t* __restrict__ Tx,
                         ushort_t* __restrict__ Exb,
                         ushort_t* __restrict__ T1, ushort_t* __restrict__ T2,
                         ushort_t* __restrict__ T3, ushort_t* __restrict__ T4,
                         ushort_t* __restrict__ T5, ushort_t* __restrict__ T6) {
    __shared__ ushort_t sm[64][65];
    int b = blockIdx.x, t = threadIdx.x;
    if (b < 12500) { cvt4(wm_x, Xb, b * 256 + t, 3200000); return; }
    b -= 12500;
    if (b < 12288) { cvt4(text, Tx, b * 256 + t, 3145728); return; }
    b -= 12288;
    if (b < 1) { cvt4(extra, Exb, t, 128); return; }
    b -= 1;
    if (b < 16) { wtx_tile(W1, T1, 256, 256, b, sm); return; }
    b -= 16;
    if (b < 16) { wtx_tile(W2, T2, 256, 256, b, sm); return; }
    b -= 16;
    if (b < 16) { wtx_tile(W3, T3, 256, 256, b, sm); return; }
    b -= 16;
    if (b < 16) { wtx_tile(W4, T4, 256, 256, b, sm); return; }
    b -= 16;
    if (b < 64) { wtx_tile(W5, T5, 1024, 256, b, sm); return; }
    b -= 64;
    wtx_tile(W6, T6, 1280, 768, b, sm);
}

// ---------------------------------------------------------------------------
// CSR build v2: 2-level LDS-atomic counting sort. NO global atomics.
// ---------------------------------------------------------------------------
#define WM_P 512
#define WM_CH 1563          // ceil(E_WM/WM_P)
#define WM_SHIFT 8
#define FS_P 128
#define FS_CH 1024          // E_F/FS_P exact
#define FS_SHIFT 6

__global__ __launch_bounds__(256) void csr_p1(const int* __restrict__ wm_dst,
                                              const int* __restrict__ f_dst,
                                              int* __restrict__ Cwm,
                                              int* __restrict__ Cfs) {
    __shared__ int hist[256];
    int b = blockIdx.x, t = threadIdx.x;
    hist[t] = 0; __syncthreads();
    if (b < WM_P) {
        int e0 = b * WM_CH, e1 = e0 + WM_CH; if (e1 > E_WM) e1 = E_WM;
        for (int e = e0 + t; e < e1; e += 256)
            atomicAdd(&hist[wm_dst[e] >> WM_SHIFT], 1);
        __syncthreads();
        Cwm[b * 256 + t] = hist[t];
    } else {
        int p = b - WM_P;
        int e0 = p * FS_CH, e1 = e0 + FS_CH;
        for (int e = e0 + t; e < e1; e += 256)
            atomicAdd(&hist[f_dst[e] >> FS_SHIFT], 1);
        __syncthreads();
        Cfs[p * 256 + t] = hist[t];
    }
}

__global__ __launch_bounds__(256) void csr_p2a(int* __restrict__ Cwm, int* __restrict__ BTwm,
                                               int* __restrict__ Cfs, int* __restrict__ BTfs) {
    __shared__ int sm[256];
    int b = blockIdx.x, t = threadIdx.x;
    int* C; int* BT; int P; int bk;
    if (b < 256) { C = Cwm; BT = BTwm; P = WM_P; bk = b; }
    else         { C = Cfs; BT = BTfs; P = FS_P; bk = b - 256; }
    int half = P >> 1;
    int v0 = 0, v1 = 0;
    if (t < half) { v0 = C[(2 * t) * 256 + bk]; v1 = C[(2 * t + 1) * 256 + bk]; }
    int s = v0 + v1;
    sm[t] = s; __syncthreads();
#pragma unroll
    for (int st = 1; st < 256; st <<= 1) {
        int x = (t >= st) ? sm[t - st] : 0;
        __syncthreads();
        sm[t] += x;
        __syncthreads();
    }
    int ex = sm[t] - s;
    if (t < half) {
        C[(2 * t) * 256 + bk] = ex;
        C[(2 * t + 1) * 256 + bk] = ex + v0;
    }
    if (t == 255) BT[bk] = sm[255];
}

__global__ __launch_bounds__(256) void csr_p2b(const int* __restrict__ BTwm,
                                               int* __restrict__ BSwm,
                                               const int* __restrict__ BTfs,
                                               int* __restrict__ BSfs) {
    __shared__ int sm[256];
    int t = threadIdx.x;
    const int* BT = blockIdx.x ? BTfs : BTwm;
    int* BS = blockIdx.x ? BSfs : BSwm;
    int E = blockIdx.x ? E_F : E_WM;
    int v = BT[t];
    sm[t] = v; __syncthreads();
#pragma unroll
    for (int st = 1; st < 256; st <<= 1) {
        int x = (t >= st) ? sm[t - st] : 0;
        __syncthreads();
        sm[t] += x;
        __syncthreads();
    }
    BS[t] = sm[t] - v;
    if (t == 255) BS[256] = E;
}

__global__ __launch_bounds__(256) void csr_p3(const int* __restrict__ wm_src,
                                              const int* __restrict__ wm_dst,
                                              const int* __restrict__ Cwm,
                                              const int* __restrict__ BSwm,
                                              int2* __restrict__ SEwm,
                                              const int* __restrict__ f_src,
                                              const int* __restrict__ f_dst,
                                              const int* __restrict__ Cfs,
                                              const int* __restrict__ BSfs,
                                              int2* __restrict__ SEfs) {
    __shared__ int cur[256];
    int b = blockIdx.x, t = threadIdx.x;
    if (b < WM_P) {
        cur[t] = Cwm[b * 256 + t] + BSwm[t];
        __syncthreads();
        int e0 = b * WM_CH, e1 = e0 + WM_CH; if (e1 > E_WM) e1 = E_WM;
        for (int e = e0 + t; e < e1; e += 256) {
            int d = wm_dst[e], s = wm_src[e];
            int pos = atomicAdd(&cur[d >> WM_SHIFT], 1);
            SEwm[pos] = make_int2(s, d);
        }
    } else {
        int p = b - WM_P;
        cur[t] = Cfs[p * 256 + t] + BSfs[t];
        __syncthreads();
        int e0 = p * FS_CH, e1 = e0 + FS_CH;
        for (int e = e0 + t; e < e1; e += 256) {
            int d = f_dst[e], s = f_src[e];
            int pos = atomicAdd(&cur[d >> FS_SHIFT], 1);
            SEfs[pos] = make_int2(s, d);
        }
    }
}

__global__ __launch_bounds__(256) void csr_p4(const int2* __restrict__ SEwm,
                                              const int* __restrict__ BSwm,
                                              int* __restrict__ wm_off,
                                              int* __restrict__ wm_bkt,
                                              const int2* __restrict__ SEfs,
                                              const int* __restrict__ BSfs,
                                              int* __restrict__ fs_off,
                                              int* __restrict__ fs_bkt) {
    __shared__ int cnt[256];
    __shared__ int sm[256];
    int ob = blockIdx.x, t = threadIdx.x;
    const int2* SE; const int* BS; int* off; int* bkt;
    int b, nb0, n, E, bw;
    if (ob < 256) { SE = SEwm; BS = BSwm; off = wm_off; bkt = wm_bkt;
                    b = ob; nb0 = b << WM_SHIFT; n = N_WM; E = E_WM; bw = 256; }
    else          { SE = SEfs; BS = BSfs; off = fs_off; bkt = fs_bkt;
                    b = ob - 256; nb0 = b << FS_SHIFT; n = N_F; E = E_F; bw = 64; }
    int e0 = BS[b], e1 = BS[b + 1];
    cnt[t] = 0; __syncthreads();
    for (int e = e0 + t; e < e1; e += 256)
        atomicAdd(&cnt[SE[e].y - nb0], 1);
    __syncthreads();
    int v = cnt[t];
    sm[t] = v; __syncthreads();
#pragma unroll
    for (int st = 1; st < 256; st <<= 1) {
        int x = (t >= st) ? sm[t - st] : 0;
        __syncthreads();
        sm[t] += x;
        __syncthreads();
    }
    int ex = sm[t] - v;
    if (t < bw && nb0 + t < n) off[nb0 + t] = e0 + ex;
    if (b == 0 && t == 0) off[n] = E;
    __syncthreads();
    cnt[t] = e0 + ex;        // cursors
    __syncthreads();
    for (int e = e0 + t; e < e1; e += 256) {
        int2 sd = SE[e];
        int pos = atomicAdd(&cnt[sd.y - nb0], 1);
        bkt[pos] = sd.x;
    }
}

// ---------------------------------------------------------------------------
// aggregate (bf16): hm[i] = h[i] + sum_{j in CSR(i)} h[bucket[j]]
// one wave per node, ushort4 (8B) per lane, fp32 accumulate.
// 16-deep manual batch -> 16 independent row gathers in flight per wave.
// ---------------------------------------------------------------------------
__global__ void aggregate_kernel(const ushort_t* __restrict__ h,
                                 const int* __restrict__ off,
                                 const int* __restrict__ bucket,
                                 ushort_t* __restrict__ hm, int n) {
    int i = blockIdx.x * 4 + (threadIdx.x >> 6);
    if (i >= n) return;
    int lane = threadIdx.x & 63;
    int s0 = off[i], s1 = off[i + 1];
    const ushort4* hp = (const ushort4*)h;   // 64 ushort4 per row
    float4 acc = bf4f(hp[(size_t)i * 64 + lane]);
    int j = s0;
    for (; j + 16 <= s1; j += 16) {
        int bb[16];
#pragma unroll
        for (int q = 0; q < 16; ++q) bb[q] = bucket[j + q];
        ushort4 rr[16];
#pragma unroll
        for (int q = 0; q < 16; ++q) rr[q] = hp[(size_t)bb[q] * 64 + lane];
#pragma unroll
        for (int q = 0; q < 16; ++q) {
            float4 v = bf4f(rr[q]);
            acc.x += v.x; acc.y += v.y; acc.z += v.z; acc.w += v.w;
        }
    }
    for (; j + 4 <= s1; j += 4) {
        int bb[4];
#pragma unroll
        for (int q = 0; q < 4; ++q) bb[q] = bucket[j + q];
        ushort4 rr[4];
#pragma unroll
        for (int q = 0; q < 4; ++q) rr[q] = hp[(size_t)bb[q] * 64 + lane];
#pragma unroll
        for (int q = 0; q < 4; ++q) {
            float4 v = bf4f(rr[q]);
            acc.x += v.x; acc.y += v.y; acc.z += v.z; acc.w += v.w;
        }
    }
    for (; j < s1; ++j) {
        float4 v = bf4f(hp[(size_t)bucket[j] * 64 + lane]);
        acc.x += v.x; acc.y += v.y; acc.z += v.z; acc.w += v.w;
    }
    ushort4 u;
    u.x = f2bf(acc.x); u.y = f2bf(acc.y); u.z = f2bf(acc.z); u.w = f2bf(acc.w);
    ((ushort4*)hm)[(size_t)i * 64 + lane] = u;
}

// ---------------------------------------------------------------------------
// tmp[i] = sum_k table[token2nodepos[i,k]+2]   (bf16 table, fp32 accumulate)
// ---------------------------------------------------------------------------
__global__ void tmp_kernel(const ushort_t* __restrict__ gemb,
                           const ushort_t* __restrict__ extra,
                           const int* __restrict__ t2np,
                           ushort_t* __restrict__ D) {
    int i = blockIdx.x * 4 + (threadIdx.x >> 6);
    int lane = threadIdx.x & 63;
    float4 s = make_float4(0.f, 0.f, 0.f, 0.f);
#pragma unroll
    for (int k = 0; k < Kc; ++k) {
        int idx = t2np[i * Kc + k] + 2;
        const ushort4* row = (idx < 2) ? (const ushort4*)(extra + (size_t)idx * Gd)
                                       : (const ushort4*)(gemb + (size_t)(idx - 2) * Gd);
        float4 v = bf4f(row[lane]);
        s.x += v.x; s.y += v.y; s.z += v.z; s.w += v.w;
    }
    ushort4 u;
    u.x = f2bf(s.x); u.y = f2bf(s.y); u.z = f2bf(s.z); u.w = f2bf(s.w);
    ((ushort4*)D)[(size_t)i * 64 + lane] = u;
}

// ---------------------------------------------------------------------------
// row gather (bf16): F[i] = E[ids[i]]
// ---------------------------------------------------------------------------
__global__ void gather_kernel(const ushort_t* __restrict__ Ein,
                              const int* __restrict__ ids,
                              ushort_t* __restrict__ F) {
    int i = blockIdx.x * 4 + (threadIdx.x >> 6);
    int lane = threadIdx.x & 63;
    ((ushort4*)F)[(size_t)i * 64 + lane] =
        ((const ushort4*)Ein)[(size_t)ids[i] * 64 + lane];
}

// ---------------------------------------------------------------------------
// bf16 MFMA GEMM, templated tile BM x BN (BK=64), lds-dma staging,
// bijective XCD swizzle, and T2 bank-conflict swizzle done rule-21-style:
// linear LDS dest (lds-dma), global SOURCE k-offset pre-XORed with
// (row&7)<<3 (8-elem aligned -> 16B contiguity preserved), ds_read XORs
// the same -> 16-way conflict becomes 2-way (free).
// MODE 0: A = p0[row][k], rowlen K
// MODE 2: A = k<256 ? p0 : p1(k-256) rowlen 768        (tmp|text), K=1024
// MODE 3: A = k<768 ? p0 : k<1024 ? p1 : p2            (text|tmp|temporal), K=1280
// OUTBF: 1 -> bf16 C, 0 -> fp32 C
// ---------------------------------------------------------------------------
#define TBK 64
#define GBM 64
#define GBN 128

__device__ __forceinline__ void xcd_swizzle(int& bx, int& by) {
    int gx = gridDim.x;
    int nwg = gx * gridDim.y;
    int orig = by * gx + bx;
    int q = nwg >> 3, r = nwg & 7;
    int xcd = orig & 7, loc = orig >> 3;
    int wg = (xcd < r ? xcd * (q + 1) : r * (q + 1) + (xcd - r) * q) + loc;
    bx = wg % gx;
    by = wg / gx;
}

template <int MODE, int OUTBF, int BM, int BN>
__global__ __launch_bounds__(256) void mfma_gemm(
    const ushort_t* __restrict__ p0, const ushort_t* __restrict__ p1,
    const ushort_t* __restrict__ p2, const ushort_t* __restrict__ Wt,
    const float* __restrict__ bias, void* __restrict__ Cv,
    int M, int N, int K, int relu) {
    constexpr int MR = BM / 32;          // m-frags per wave (2 waves in M)
    constexpr int NR = BN / 32;          // n-frags per wave (2 waves in N)
    constexpr int A_IT = (BM * TBK) / 2048;
    constexpr int B_IT = (BN * TBK) / 2048;
    __shared__ ushort_t As[BM * TBK];    // [row][k] linear (lds-dma dest)
    __shared__ ushort_t Bs[BN * TBK];    // [col][k] linear

    int tid  = threadIdx.x;
    int lane = tid & 63;
    int wave = tid >> 6;
    int wm = (wave >> 1) * (BM / 2), wn = (wave & 1) * (BN / 2);
    int bx = blockIdx.x, by = blockIdx.y;
    xcd_swizzle(bx, by);
    int row0 = by * BM, col0 = bx * BN;
    int l15 = lane & 15, l4 = lane >> 4;

    f32x4 acc[MR][NR];
#pragma unroll
    for (int i = 0; i < MR; ++i)
#pragma unroll
        for (int j = 0; j < NR; ++j)
            acc[i][j] = (f32x4){0.f, 0.f, 0.f, 0.f};

    for (int k0 = 0; k0 < K; k0 += TBK) {
        // ---- stage A via lds-dma (pre-swizzled global source) ----
#pragma unroll
        for (int it = 0; it < A_IT; ++it) {
            int eb = it * 2048 + wave * 512;   // wave-uniform elem base
            int le = eb + lane * 8;
            int r  = le >> 6;
            int kl = (le ^ ((r & 7) << 3)) & 63;   // T2 source pre-swizzle
            int grow = row0 + r; if (grow > M - 1) grow = M - 1;
            int gk = k0 + kl;
            const ushort_t* gp;
            if (MODE == 0)
                gp = p0 + (size_t)grow * K + gk;
            else if (MODE == 2)
                gp = (gk < 256) ? p0 + (size_t)grow * 256 + gk
                                : p1 + (size_t)grow * 768 + (gk - 256);
            else
                gp = (gk < 768) ? p0 + (size_t)grow * 768 + gk
                   : (gk < 1024) ? p1 + (size_t)grow * 256 + (gk - 768)
                                 : p2 + (size_t)grow * 256 + (gk - 1024);
            gl2lds16(gp, &As[eb]);
        }
        // ---- stage B via lds-dma ----
#pragma unroll
        for (int it = 0; it < B_IT; ++it) {
            int eb = it * 2048 + wave * 512;
            int le = eb + lane * 8;
            int nl = le >> 6;
            int kl = (le ^ ((nl & 7) << 3)) & 63;
            const ushort_t* gp = Wt + (size_t)(col0 + nl) * K + k0 + kl;
            gl2lds16(gp, &Bs[eb]);
        }
        __syncthreads();

#pragma unroll
        for (int ks = 0; ks < TBK; ks += 32) {
            short8 af[MR], bfr[NR];
#pragma unroll
            for (int mi = 0; mi < MR; ++mi) {
                int row = wm + mi * 16 + l15;
                int col = (ks + l4 * 8) ^ ((row & 7) << 3);
                af[mi] = *(const short8*)&As[row * TBK + col];
            }
#pragma unroll
            for (int ni = 0; ni < NR; ++ni) {
                int row = wn + ni * 16 + l15;
                int col = (ks + l4 * 8) ^ ((row & 7) << 3);
                bfr[ni] = *(const short8*)&Bs[row * TBK + col];
            }
#pragma unroll
            for (int mi = 0; mi < MR; ++mi)
#pragma unroll
                for (int ni = 0; ni < NR; ++ni)
                    acc[mi][ni] = __builtin_amdgcn_mfma_f32_16x16x32_bf16(
                        af[mi], bfr[ni], acc[mi][ni], 0, 0, 0);
        }
        __syncthreads();
    }

    // ---- epilogue: bias (+relu); C/D layout col=lane&15, row=(lane>>4)*4+reg ----
#pragma unroll
    for (int ni = 0; ni < NR; ++ni) {
        int c = col0 + wn + ni * 16 + l15;
        float bv = bias[c];
#pragma unroll
        for (int mi = 0; mi < MR; ++mi) {
#pragma unroll
            for (int r = 0; r < 4; ++r) {
                int rr = row0 + wm + mi * 16 + l4 * 4 + r;
                if (rr < M) {
                    float v = acc[mi][ni][r] + bv;
                    if (relu) v = fmaxf(v, 0.f);
                    if (OUTBF) ((ushort_t*)Cv)[(size_t)rr * N + c] = f2bf(v);
                    else       ((float*)Cv)[(size_t)rr * N + c] = v;
                }
            }
        }
    }
}

// ---------------------------------------------------------------------------
extern "C" void kernel_launch(void* const* d_in, const int* in_sizes, int n_in,
                              void* d_out, int out_size, void* d_ws, size_t ws_size,
                              hipStream_t stream) {
    const float* text    = (const float*)d_in[0];   // [16384, 768]
    const float* wm_x    = (const float*)d_in[1];   // [50000, 256]
    const int*   wm_ei   = (const int*)d_in[2];     // [2, 800000]
    const int*   t2np    = (const int*)d_in[3];     // [16384, 4]
    const int*   f_ids   = (const int*)d_in[4];     // [16384]
    const int*   f_ei    = (const int*)d_in[5];     // [2, 131072]
    const float* extra   = (const float*)d_in[6];   // [2, 256]
    const float* wm_W1   = (const float*)d_in[7];
    const float* wm_b1   = (const float*)d_in[8];
    const float* wm_W2   = (const float*)d_in[9];
    const float* wm_b2   = (const float*)d_in[10];
    const float* fs_W1   = (const float*)d_in[11];
    const float* fs_b1   = (const float*)d_in[12];
    const float* fs_W2   = (const float*)d_in[13];
    const float* fs_b2   = (const float*)d_in[14];
    const float* fc1_W   = (const float*)d_in[15];  // [1024, 256]
    const float* fc1_b   = (const float*)d_in[16];
    const float* fc3_W   = (const float*)d_in[17];  // [1280, 768]
    const float* fc3_b   = (const float*)d_in[18];
    float* out = (float*)d_out;                     // [16384, 768]

    // ---- workspace layout (bf16 = ushort) ----
    ushort_t* Xb  = (ushort_t*)d_ws;            // [50000*256] wm_x bf16 (reused: h1)
    ushort_t* Ag  = Xb + 12800000;              // [50000*256] aggregate out
    ushort_t* Gm  = Ag + 12800000;              // [50000*256] gemb (reused: F, H)
    ushort_t* Tx  = Gm + 12800000;              // [16384*768] text bf16
    ushort_t* Dt  = Tx + 12582912;              // [16384*256] tmp
    ushort_t* Ee  = Dt + 4194304;               // [16384*256] gte (reused: T)
    ushort_t* Wv  = Ee + 4194304;               // weights, transposed bf16
    ushort_t* wt_wm1 = Wv;                      //  65536
    ushort_t* wt_wm2 = wt_wm1 + 65536;          //  65536
    ushort_t* wt_fs1 = wt_wm2 + 65536;          //  65536
    ushort_t* wt_fs2 = wt_fs1 + 65536;          //  65536
    ushort_t* wt_fc1 = wt_fs2 + 65536;          //  262144
    ushort_t* wt_fc3 = wt_fc1 + 262144;         //  983040
    ushort_t* Exb    = wt_fc3 + 983040;         //  512
    // persistent CSR outputs
    int* wm_off = (int*)(Exb + 512);            // [N_WM+1]
    int* fs_off = wm_off + N_WM + 1;            // [N_F+1]
    int* wm_bkt = fs_off + N_F + 1;             // [E_WM]
    int* fs_bkt = wm_bkt + E_WM;                // [E_F]
    // CSR-build scratch overlaid on Ag (dead until first aggregate)
    int2* SEwm = (int2*)Ag;                     // [E_WM] int2 (6.4MB)
    int2* SEfs = SEwm + E_WM;                   // [E_F]  int2 (1.05MB)
    int*  Cwm  = (int*)(SEfs + E_F);            // [WM_P*256]
    int*  Cfs  = Cwm + WM_P * 256;              // [FS_P*256]
    int*  BTwm = Cfs + FS_P * 256;              // [256]
    int*  BTfs = BTwm + 256;                    // [256]
    int*  BSwm = BTfs + 256;                    // [257]
    int*  BSfs = BSwm + 257;                    // [257]

    ushort_t* h1 = Xb;                 // gemm1 out overwrites Xb (dead)
    ushort_t* F  = Gm;                 // gather out overwrites gemb (dead)
    ushort_t* H  = Gm + 4194304;
    ushort_t* T  = Ee;                 // fstm out overwrites Ee (dead)

    const int* wm_src = wm_ei;
    const int* wm_dst = wm_ei + E_WM;
    const int* f_src  = f_ei;
    const int* f_dst  = f_ei + E_F;

    dim3 blk(256);
    dim3 gW(Gd / GBN, (N_WM + GBM - 1) / GBM);   // 2 x 782
    dim3 gF(Gd / GBN, N_F / GBM);                // 2 x 256
    dim3 gO(PLM / GBN, N_F / GBM);               // 6 x 256

    // ===== CSR build (counting sort, LDS atomics only) =====
    csr_p1<<<WM_P + FS_P, blk, 0, stream>>>(wm_dst, f_dst, Cwm, Cfs);
    csr_p2a<<<512, blk, 0, stream>>>(Cwm, BTwm, Cfs, BTfs);
    csr_p2b<<<2, blk, 0, stream>>>(BTwm, BSwm, BTfs, BSfs);
    csr_p3<<<WM_P + FS_P, blk, 0, stream>>>(wm_src, wm_dst, Cwm, BSwm, SEwm,
                                            f_src, f_dst, Cfs, BSfs, SEfs);
    csr_p4<<<512, blk, 0, stream>>>(SEwm, BSwm, wm_off, wm_bkt,
                                    SEfs, BSfs, fs_off, fs_bkt);

    // ===== one-time conversions (fused) =====
    conv_all<<<25157, blk, 0, stream>>>(wm_x, text, extra,
                                        wm_W1, wm_W2, fs_W1, fs_W2, fc1_W, fc3_W,
                                        Xb, Tx, Exb,
                                        wt_wm1, wt_wm2, wt_fs1, wt_fs2,
                                        wt_fc1, wt_fc3);

    // ===== WM layer 1 =====
    aggregate_kernel<<<(N_WM + 3) / 4, blk, 0, stream>>>(Xb, wm_off, wm_bkt, Ag, N_WM);
    mfma_gemm<0, 1, GBM, GBN><<<gW, blk, 0, stream>>>(Ag, nullptr, nullptr, wt_wm1,
                                                      wm_b1, h1, N_WM, Gd, Gd, 1);
    // ===== WM layer 2 =====
    aggregate_kernel<<<(N_WM + 3) / 4, blk, 0, stream>>>(h1, wm_off, wm_bkt, Ag, N_WM);
    mfma_gemm<0, 1, GBM, GBN><<<gW, blk, 0, stream>>>(Ag, nullptr, nullptr, wt_wm2,
                                                      wm_b2, Gm, N_WM, Gd, Gd, 1);
    // ===== tmp =====
    tmp_kernel<<<N_F / 4, blk, 0, stream>>>(Gm, Exb, t2np, Dt);
    // ===== fc1: Ee = concat(tmp, text) @ fc1_W + b =====
    mfma_gemm<2, 1, GBM, GBN><<<gF, blk, 0, stream>>>(Dt, Tx, nullptr, wt_fc1,
                                                      fc1_b, Ee, N_F, Gd, Gd + PLM, 0);
    // ===== FSTM gather =====
    gather_kernel<<<N_F / 4, blk, 0, stream>>>(Ee, f_ids, F);
    // ===== FSTM layer 1 =====
    aggregate_kernel<<<N_F / 4, blk, 0, stream>>>(F, fs_off, fs_bkt, Ag, N_F);
    mfma_gemm<0, 1, GBM, GBN><<<gF, blk, 0, stream>>>(Ag, nullptr, nullptr, wt_fs1,
                                                      fs_b1, H, N_F, Gd, Gd, 1);
    // ===== FSTM layer 2 =====
    aggregate_kernel<<<N_F / 4, blk, 0, stream>>>(H, fs_off, fs_bkt, Ag, N_F);
    mfma_gemm<0, 1, GBM, GBN><<<gF, blk, 0, stream>>>(Ag, nullptr, nullptr, wt_fs2,
                                                      fs_b2, T, N_F, Gd, Gd, 1);
    // ===== fc3: out = concat(text, tmp, temporal) @ fc3_W + b (fp32 out) =====
    mfma_gemm<3, 0, GBM, GBN><<<gO, blk, 0, stream>>>(Tx, Dt, T, wt_fc3, fc3_b,
                                                      out, N_F, PLM, PLM + 2 * Gd, 0);
}